// Round 1
// baseline (956.775 us; speedup 1.0000x reference)
//
#include <hip/hip_runtime.h>

// ---------------------------------------------------------------------------
// QMixtralAttention: rmsnorm -> int8 fake-quant -> QKV proj (exact int-in-bf16
// MFMA) -> int4 KV-cache quant -> RoPE -> causal GQA flash attention (bf16
// MFMA) -> int8 fake-quant -> O proj.  B=1 S=2048 H=4096 NH=32 HD=128 NKV=8.
// ---------------------------------------------------------------------------

#define SQ   2048
#define HID  4096
#define NHEAD 32
#define HDIM 128
#define NKVH 8
#define KVD  1024   // NKVH*HDIM

typedef __attribute__((ext_vector_type(8))) short          bh8;   // 8 x bf16 bits (MFMA operand)
typedef __attribute__((ext_vector_type(8))) unsigned short us8;
typedef __attribute__((ext_vector_type(4))) unsigned short us4;
typedef __attribute__((ext_vector_type(4))) float          f4v;

__device__ __forceinline__ unsigned short f2bf(float f) {
    unsigned u = __float_as_uint(f);
    u += 0x7fffu + ((u >> 16) & 1u);          // RNE
    return (unsigned short)(u >> 16);
}

// ---------------------------------------------------------------------------
// Per-row (4096-wide) symmetric int8 fake-quant, optional fused RMSNorm.
// Used for: weight rows (do_rms=0), hidden states (do_rms=1), attn out (0).
// Writes integer-valued bf16 (exact) + per-row scale.
// ---------------------------------------------------------------------------
__global__ __launch_bounds__(256) void rowquant_kernel(
    const float* __restrict__ X, const float* __restrict__ Wg,
    unsigned short* __restrict__ Q, float* __restrict__ Sout, int do_rms)
{
    int row = blockIdx.x;
    int tid = threadIdx.x;
    int l = tid & 63, wv = tid >> 6;
    const float* xr = X + (size_t)row * 4096;
    float v[16];
#pragma unroll
    for (int i = 0; i < 4; i++) {
        float4 f = ((const float4*)xr)[i * 256 + tid];
        v[4*i+0] = f.x; v[4*i+1] = f.y; v[4*i+2] = f.z; v[4*i+3] = f.w;
    }
    __shared__ float red[4];
    if (do_rms) {
        float ss = 0.f;
#pragma unroll
        for (int i = 0; i < 16; i++) ss += v[i] * v[i];
#pragma unroll
        for (int o = 32; o >= 1; o >>= 1) ss += __shfl_xor(ss, o);
        if (l == 0) red[wv] = ss;
        __syncthreads();
        float tot = red[0] + red[1] + red[2] + red[3];
        float rs = rsqrtf(tot * (1.0f / 4096.0f) + 1e-5f);
        __syncthreads();   // red is reused below
#pragma unroll
        for (int i = 0; i < 4; i++) {
            float4 wf = ((const float4*)Wg)[i * 256 + tid];
            v[4*i+0] = v[4*i+0] * rs * wf.x;
            v[4*i+1] = v[4*i+1] * rs * wf.y;
            v[4*i+2] = v[4*i+2] * rs * wf.z;
            v[4*i+3] = v[4*i+3] * rs * wf.w;
        }
    }
    float am = 0.f;
#pragma unroll
    for (int i = 0; i < 16; i++) am = fmaxf(am, fabsf(v[i]));
#pragma unroll
    for (int o = 32; o >= 1; o >>= 1) am = fmaxf(am, __shfl_xor(am, o));
    if (l == 0) red[wv] = am;
    __syncthreads();
    am = fmaxf(fmaxf(red[0], red[1]), fmaxf(red[2], red[3]));
    float s = fmaxf(am / 127.0f, 1e-8f);
    if (tid == 0) Sout[row] = s;
    unsigned short qb[16];
#pragma unroll
    for (int i = 0; i < 16; i++) {
        float q = rintf(v[i] / s);                 // true division: match jnp rounding
        q = fminf(fmaxf(q, -127.f), 127.f);
        qb[i] = f2bf(q);                           // integer <=127: exact in bf16
    }
    unsigned short* qr = Q + (size_t)row * 4096;
#pragma unroll
    for (int i = 0; i < 4; i++) {
        us4 o4 = { qb[4*i+0], qb[4*i+1], qb[4*i+2], qb[4*i+3] };
        ((us4*)qr)[i * 256 + tid] = o4;
    }
}

// ---------------------------------------------------------------------------
// bf16 GEMM: C[m][n] = sa[m]*sb[n] * sum_k A[m][k]*B[n][k]   (both K-major)
// 128x128 tile, BK=64, 4 waves (2x2), 16x16x32 MFMA, reg-staged LDS (pad 72).
// ---------------------------------------------------------------------------
__global__ __launch_bounds__(256) void gemm_bf16(
    const unsigned short* __restrict__ A, const unsigned short* __restrict__ B,
    const float* __restrict__ sa, const float* __restrict__ sb,
    float* __restrict__ C, int M, int N, int K)
{
    __shared__ unsigned short As[128 * 72];
    __shared__ unsigned short Bs[128 * 72];
    int tid = threadIdx.x;
    int l = tid & 63, w = tid >> 6;
    int wr = w >> 1, wc = w & 1;
    int g = l >> 4, c = l & 15;
    int bn = blockIdx.x, bm = blockIdx.y;
    const unsigned short* Ab = A + (size_t)bm * 128 * K;
    const unsigned short* Bb = B + (size_t)bn * 128 * K;
    f4v acc[4][4] = {};
    int kt = K >> 6;
    for (int t = 0; t < kt; t++) {
        int k0 = t * 64;
#pragma unroll
        for (int j = 0; j < 4; j++) {
            int e = (j * 256 + tid) * 8;
            int r = e >> 6, cc = e & 63;
            us8 av = *(const us8*)(Ab + (size_t)r * K + k0 + cc);
            us8 bv = *(const us8*)(Bb + (size_t)r * K + k0 + cc);
            *(us8*)(As + r * 72 + cc) = av;
            *(us8*)(Bs + r * 72 + cc) = bv;
        }
        __syncthreads();
#pragma unroll
        for (int kk = 0; kk < 2; kk++) {
            bh8 af[4], bf[4];
#pragma unroll
            for (int m = 0; m < 4; m++)
                af[m] = *(const bh8*)(As + (wr * 64 + m * 16 + c) * 72 + kk * 32 + g * 8);
#pragma unroll
            for (int n = 0; n < 4; n++)
                bf[n] = *(const bh8*)(Bs + (wc * 64 + n * 16 + c) * 72 + kk * 32 + g * 8);
#pragma unroll
            for (int m = 0; m < 4; m++)
#pragma unroll
                for (int n = 0; n < 4; n++)
                    acc[m][n] = __builtin_amdgcn_mfma_f32_16x16x32_bf16(af[m], bf[n], acc[m][n], 0, 0, 0);
        }
        __syncthreads();
    }
#pragma unroll
    for (int m = 0; m < 4; m++) {
#pragma unroll
        for (int j = 0; j < 4; j++) {
            int row = bm * 128 + wr * 64 + m * 16 + g * 4 + j;   // C/D: row=(l>>4)*4+reg
            float sr = sa[row];
#pragma unroll
            for (int n = 0; n < 4; n++) {
                int col = bn * 128 + wc * 64 + n * 16 + c;       // C/D: col=l&15
                C[(size_t)row * N + col] = acc[m][n][j] * sr * sb[col];
            }
        }
    }
}

// ---------------------------------------------------------------------------
// K path: int4 asym group quant (group=128 == one kv head) then RoPE, -> bf16.
// One wave per (token, kv-head); lane l owns the (d=l, d=l+64) rope pair.
// ---------------------------------------------------------------------------
__global__ __launch_bounds__(256) void k_quant_rope(
    const float* __restrict__ Kf, const int* __restrict__ pos,
    unsigned short* __restrict__ Kb)
{
    int wid = blockIdx.x * 4 + (threadIdx.x >> 6);
    int l = threadIdx.x & 63;
    int t = wid >> 3, kvh = wid & 7;
    const float* gp = Kf + (size_t)t * KVD + kvh * 128;
    float x1 = gp[l], x2 = gp[l + 64];
    float mn = fminf(x1, x2), mx = fmaxf(x1, x2);
#pragma unroll
    for (int o = 32; o >= 1; o >>= 1) {
        mn = fminf(mn, __shfl_xor(mn, o));
        mx = fmaxf(mx, __shfl_xor(mx, o));
    }
    float sc = fmaxf((mx - mn) / 15.0f, 1e-8f);
    float q1 = fminf(fmaxf(rintf((x1 - mn) / sc), 0.f), 15.f);
    float q2 = fminf(fmaxf(rintf((x2 - mn) / sc), 0.f), 15.f);
    x1 = q1 * sc + mn;
    x2 = q2 * sc + mn;
    float f = exp2f(-(float)l * 0.3114307588956902f);   // log2(1e6)/64
    float ang = (float)pos[t] * f;
    float cs = cosf(ang), sn = sinf(ang);
    unsigned short* op = Kb + (size_t)t * KVD + kvh * 128;
    op[l]      = f2bf(x1 * cs - x2 * sn);
    op[l + 64] = f2bf(x2 * cs + x1 * sn);
}

__global__ __launch_bounds__(256) void q_rope(
    const float* __restrict__ Qf, const int* __restrict__ pos,
    unsigned short* __restrict__ Qb)
{
    int wid = blockIdx.x * 4 + (threadIdx.x >> 6);
    int l = threadIdx.x & 63;
    int t = wid >> 5, h = wid & 31;
    const float* gp = Qf + (size_t)t * HID + h * 128;
    float x1 = gp[l], x2 = gp[l + 64];
    float f = exp2f(-(float)l * 0.3114307588956902f);
    float ang = (float)pos[t] * f;
    float cs = cosf(ang), sn = sinf(ang);
    unsigned short* op = Qb + (size_t)t * HID + h * 128;
    op[l]      = f2bf(x1 * cs - x2 * sn);
    op[l + 64] = f2bf(x2 * cs + x1 * sn);
}

__global__ __launch_bounds__(256) void v_quant(
    const float* __restrict__ Vf, unsigned short* __restrict__ Vbq)
{
    int wid = blockIdx.x * 4 + (threadIdx.x >> 6);
    int l = threadIdx.x & 63;
    int t = wid >> 3, kvh = wid & 7;
    const float* gp = Vf + (size_t)t * KVD + kvh * 128;
    float x1 = gp[l], x2 = gp[l + 64];
    float mn = fminf(x1, x2), mx = fmaxf(x1, x2);
#pragma unroll
    for (int o = 32; o >= 1; o >>= 1) {
        mn = fminf(mn, __shfl_xor(mn, o));
        mx = fmaxf(mx, __shfl_xor(mx, o));
    }
    float sc = fmaxf((mx - mn) / 15.0f, 1e-8f);
    float q1 = fminf(fmaxf(rintf((x1 - mn) / sc), 0.f), 15.f);
    float q2 = fminf(fmaxf(rintf((x2 - mn) / sc), 0.f), 15.f);
    unsigned short* op = Vbq + (size_t)t * KVD + kvh * 128;
    op[l]      = f2bf(q1 * sc + mn);
    op[l + 64] = f2bf(q2 * sc + mn);
}

// bf16 transpose [SQ][KVD] -> [KVD][SQ] via 64x64 LDS tiles
__global__ __launch_bounds__(256) void transpose_bf16(
    const unsigned short* __restrict__ in, unsigned short* __restrict__ out)
{
    __shared__ unsigned short tile[64][72];
    int bx = blockIdx.x;            // KVD/64
    int by = blockIdx.y;            // SQ/64
    int tid = threadIdx.x;
    int r = tid >> 3;
    int c8 = (tid & 7) * 8;
#pragma unroll
    for (int i = 0; i < 2; i++) {
        int rr = i * 32 + r;
        us8 v = *(const us8*)(in + (size_t)(by * 64 + rr) * KVD + bx * 64 + c8);
        *(us8*)(&tile[rr][c8]) = v;
    }
    __syncthreads();
#pragma unroll
    for (int i = 0; i < 2; i++) {
        int rr = i * 32 + r;
        us8 v;
#pragma unroll
        for (int j = 0; j < 8; j++) v[j] = tile[c8 + j][rr];
        *(us8*)(out + (size_t)(bx * 64 + rr) * SQ + by * 64 + c8) = v;
    }
}

// ---------------------------------------------------------------------------
// Causal GQA flash attention.  Block = (64-row Q tile, head); 4 waves x 16 rows.
// KVBLK=64.  Q/K/V bf16, accum fp32.  V supplied transposed [kvh*128+d][t].
// ---------------------------------------------------------------------------
__global__ __launch_bounds__(256) void attn_kernel(
    const unsigned short* __restrict__ Qb, const unsigned short* __restrict__ Kb,
    const unsigned short* __restrict__ Vbt, float* __restrict__ AO)
{
    const float SC  = 0.08838834764831845f;       // 1/sqrt(128)
    const float L2E = 1.44269504088896340736f;
    int qt = blockIdx.x, h = blockIdx.y;
    int kvh = h >> 2;                              // NREP=4, consecutive repeat
    int tid = threadIdx.x;
    int l = tid & 63, w = tid >> 6;
    int g = l >> 4, c = l & 15;
    __shared__ unsigned short Plds[4][16][72];
    int q0 = qt * 64 + w * 16;

    bh8 qf[4];
    const unsigned short* qrow = Qb + (size_t)(q0 + c) * HID + h * 128;
#pragma unroll
    for (int kk = 0; kk < 4; kk++) qf[kk] = *(const bh8*)(qrow + kk * 32 + g * 8);

    f4v acc[8] = {};
    float mrun[4] = { -1e30f, -1e30f, -1e30f, -1e30f };
    float lrun[4] = { 0.f, 0.f, 0.f, 0.f };

    for (int t = 0; t <= qt; t++) {
        int kv0 = t * 64;
        // S = Q K^T  (16 q-rows x 64 keys per wave)
        f4v sf[4];
#pragma unroll
        for (int n = 0; n < 4; n++) {
            f4v a = {};
            const unsigned short* krow = Kb + (size_t)(kv0 + n * 16 + c) * KVD + kvh * 128;
#pragma unroll
            for (int kk = 0; kk < 4; kk++) {
                bh8 kf = *(const bh8*)(krow + kk * 32 + g * 8);
                a = __builtin_amdgcn_mfma_f32_16x16x32_bf16(qf[kk], kf, a, 0, 0, 0);
            }
            sf[n] = a;
        }
        // scale + causal mask + row max (C layout: row=g*4+j, col=n*16+c)
        float pmax[4] = { -1e30f, -1e30f, -1e30f, -1e30f };
#pragma unroll
        for (int n = 0; n < 4; n++) {
            int col = kv0 + n * 16 + c;
#pragma unroll
            for (int j = 0; j < 4; j++) {
                int row = q0 + g * 4 + j;
                float sv = (col <= row) ? sf[n][j] * SC : -1e30f;
                sf[n][j] = sv;
                pmax[j] = fmaxf(pmax[j], sv);
            }
        }
        float alpha[4];
#pragma unroll
        for (int j = 0; j < 4; j++) {
            float m = pmax[j];
            m = fmaxf(m, __shfl_xor(m, 1));
            m = fmaxf(m, __shfl_xor(m, 2));
            m = fmaxf(m, __shfl_xor(m, 4));
            m = fmaxf(m, __shfl_xor(m, 8));
            float mnew = fmaxf(mrun[j], m);
            alpha[j] = exp2f((mrun[j] - mnew) * L2E);
            mrun[j] = mnew;
            lrun[j] *= alpha[j];
        }
        float rsum[4] = { 0.f, 0.f, 0.f, 0.f };
#pragma unroll
        for (int n = 0; n < 4; n++) {
#pragma unroll
            for (int j = 0; j < 4; j++) {
                float pv = exp2f((sf[n][j] - mrun[j]) * L2E);
                sf[n][j] = pv;
                rsum[j] += pv;
            }
        }
#pragma unroll
        for (int j = 0; j < 4; j++) {
            float r = rsum[j];
            r += __shfl_xor(r, 1);
            r += __shfl_xor(r, 2);
            r += __shfl_xor(r, 4);
            r += __shfl_xor(r, 8);
            lrun[j] += r;
        }
#pragma unroll
        for (int n = 0; n < 8; n++) {
#pragma unroll
            for (int j = 0; j < 4; j++) acc[n][j] *= alpha[j];
        }
        // P: C-layout -> bf16 -> LDS -> A-layout
#pragma unroll
        for (int n = 0; n < 4; n++) {
#pragma unroll
            for (int j = 0; j < 4; j++)
                Plds[w][g * 4 + j][n * 16 + c] = f2bf(sf[n][j]);
        }
        __syncthreads();
#pragma unroll
        for (int kk = 0; kk < 2; kk++) {
            bh8 pa = *(const bh8*)(&Plds[w][c][kk * 32 + g * 8]);
#pragma unroll
            for (int n = 0; n < 8; n++) {
                const unsigned short* vrow =
                    Vbt + (size_t)(kvh * 128 + n * 16 + c) * SQ + kv0 + kk * 32 + g * 8;
                bh8 vf = *(const bh8*)(vrow);
                acc[n] = __builtin_amdgcn_mfma_f32_16x16x32_bf16(pa, vf, acc[n], 0, 0, 0);
            }
        }
        __syncthreads();
    }
#pragma unroll
    for (int j = 0; j < 4; j++) {
        int row = q0 + g * 4 + j;
        float inv = 1.0f / lrun[j];
#pragma unroll
        for (int n = 0; n < 8; n++)
            AO[(size_t)row * HID + h * 128 + n * 16 + c] = acc[n][j] * inv;
    }
}

// ---------------------------------------------------------------------------
extern "C" void kernel_launch(void* const* d_in, const int* in_sizes, int n_in,
                              void* d_out, int out_size, void* d_ws, size_t ws_size,
                              hipStream_t stream)
{
    const float* x   = (const float*)d_in[0];
    const int*   pos = (const int*)d_in[1];
    const float* rw  = (const float*)d_in[2];
    const float* Wq  = (const float*)d_in[3];
    const float* Wk  = (const float*)d_in[4];
    const float* Wv  = (const float*)d_in[5];
    const float* Wo  = (const float*)d_in[6];
    float* out = (float*)d_out;

    char* p = (char*)d_ws;
    auto alloc = [&](size_t bytes) -> void* {
        void* r = (void*)p;
        p += (bytes + 255) & ~(size_t)255;
        return r;
    };
    unsigned short* xq   = (unsigned short*)alloc((size_t)SQ * HID * 2);
    float*          sx   = (float*)alloc(SQ * 4);
    unsigned short* wqq  = (unsigned short*)alloc((size_t)HID * HID * 2);
    unsigned short* wkq  = (unsigned short*)alloc((size_t)KVD * HID * 2);
    unsigned short* wvq  = (unsigned short*)alloc((size_t)KVD * HID * 2);
    unsigned short* woq  = (unsigned short*)alloc((size_t)HID * HID * 2);
    float*          swq  = (float*)alloc(HID * 4);
    float*          swk  = (float*)alloc(KVD * 4);
    float*          swv  = (float*)alloc(KVD * 4);
    float*          swo  = (float*)alloc(HID * 4);
    float*          Qf   = (float*)alloc((size_t)SQ * HID * 4);     // reused as AO
    float*          Kf   = (float*)alloc((size_t)SQ * KVD * 4);     // Kf+Vf contiguous:
    float*          Vf   = (float*)alloc((size_t)SQ * KVD * 4);     //  reused as attq
    unsigned short* Qb   = (unsigned short*)alloc((size_t)SQ * HID * 2);
    unsigned short* Kb   = (unsigned short*)alloc((size_t)SQ * KVD * 2);
    unsigned short* Vbq  = (unsigned short*)alloc((size_t)SQ * KVD * 2);
    unsigned short* Vbt  = (unsigned short*)alloc((size_t)SQ * KVD * 2);
    float*          sa   = (float*)alloc(SQ * 4);

    size_t need = (size_t)(p - (char*)d_ws);
    if (ws_size < need) {
        // sentinel: absmax ~3.4e38 tells us ws was too small
        hipMemsetAsync(d_out, 0x7f, 4, stream);
        return;
    }
    float*          AO   = Qf;                       // Qf dead after q_rope
    unsigned short* attq = (unsigned short*)Kf;      // Kf/Vf dead after quant+rope
    // 1) weight fake-quant (per output channel)
    rowquant_kernel<<<HID, 256, 0, stream>>>(Wq, nullptr, wqq, swq, 0);
    rowquant_kernel<<<KVD, 256, 0, stream>>>(Wk, nullptr, wkq, swk, 0);
    rowquant_kernel<<<KVD, 256, 0, stream>>>(Wv, nullptr, wvq, swv, 0);
    rowquant_kernel<<<HID, 256, 0, stream>>>(Wo, nullptr, woq, swo, 0);
    // 2) rmsnorm + per-token int8 fake-quant
    rowquant_kernel<<<SQ, 256, 0, stream>>>(x, rw, xq, sx, 1);
    // 3) Q/K/V projections (exact integer math in bf16 MFMA)
    gemm_bf16<<<dim3(HID / 128, SQ / 128), 256, 0, stream>>>(xq, wqq, sx, swq, Qf, SQ, HID, HID);
    gemm_bf16<<<dim3(KVD / 128, SQ / 128), 256, 0, stream>>>(xq, wkq, sx, swk, Kf, SQ, KVD, HID);
    gemm_bf16<<<dim3(KVD / 128, SQ / 128), 256, 0, stream>>>(xq, wvq, sx, swv, Vf, SQ, KVD, HID);
    // 4) K int4 quant + RoPE ; Q RoPE ; V int4 quant + transpose
    k_quant_rope<<<SQ * NKVH / 4, 256, 0, stream>>>(Kf, pos, Kb);
    q_rope<<<SQ * NHEAD / 4, 256, 0, stream>>>(Qf, pos, Qb);
    v_quant<<<SQ * NKVH / 4, 256, 0, stream>>>(Vf, Vbq);
    transpose_bf16<<<dim3(KVD / 64, SQ / 64), 256, 0, stream>>>(Vbq, Vbt);
    // 5) causal GQA flash attention
    attn_kernel<<<dim3(SQ / 64, NHEAD), 256, 0, stream>>>(Qb, Kb, Vbt, AO);
    // 6) per-token int8 fake-quant of attention output + O projection
    rowquant_kernel<<<SQ, 256, 0, stream>>>(AO, nullptr, attq, sa, 0);
    gemm_bf16<<<dim3(HID / 128, SQ / 128), 256, 0, stream>>>(attq, woq, sa, swo, out, SQ, HID, HID);
}

// Round 2
// 645.494 us; speedup vs baseline: 1.4822x; 1.4822x over previous
//
#include <hip/hip_runtime.h>

// ---------------------------------------------------------------------------
// QMixtralAttention: rmsnorm -> int8 fake-quant -> QKV proj (exact int-in-bf16
// MFMA) -> int4 KV-cache quant -> RoPE -> causal GQA flash attention (bf16
// MFMA) -> int8 fake-quant -> O proj.  B=1 S=2048 H=4096 NH=32 HD=128 NKV=8.
// ---------------------------------------------------------------------------

#define SQ   2048
#define HID  4096
#define NHEAD 32
#define HDIM 128
#define NKVH 8
#define KVD  1024   // NKVH*HDIM

typedef __attribute__((ext_vector_type(8))) short          bh8;   // 8 x bf16 bits (MFMA operand)
typedef __attribute__((ext_vector_type(8))) unsigned short us8;
typedef __attribute__((ext_vector_type(4))) unsigned short us4;
typedef __attribute__((ext_vector_type(4))) float          f4v;

__device__ __forceinline__ unsigned short f2bf(float f) {
    unsigned u = __float_as_uint(f);
    u += 0x7fffu + ((u >> 16) & 1u);          // RNE
    return (unsigned short)(u >> 16);
}

// async global -> LDS, 16B per lane (m97 pattern)
__device__ __forceinline__ void gl2lds16(const unsigned short* g, unsigned short* l) {
    __builtin_amdgcn_global_load_lds(
        (const __attribute__((address_space(1))) unsigned int*)g,
        (__attribute__((address_space(3))) unsigned int*)l, 16, 0, 0);
}

// ---------------------------------------------------------------------------
// Per-row (4096-wide) symmetric int8 fake-quant, optional fused RMSNorm.
// ---------------------------------------------------------------------------
__global__ __launch_bounds__(256) void rowquant_kernel(
    const float* __restrict__ X, const float* __restrict__ Wg,
    unsigned short* __restrict__ Q, float* __restrict__ Sout, int do_rms)
{
    int row = blockIdx.x;
    int tid = threadIdx.x;
    int l = tid & 63, wv = tid >> 6;
    const float* xr = X + (size_t)row * 4096;
    float v[16];
#pragma unroll
    for (int i = 0; i < 4; i++) {
        float4 f = ((const float4*)xr)[i * 256 + tid];
        v[4*i+0] = f.x; v[4*i+1] = f.y; v[4*i+2] = f.z; v[4*i+3] = f.w;
    }
    __shared__ float red[4];
    if (do_rms) {
        float ss = 0.f;
#pragma unroll
        for (int i = 0; i < 16; i++) ss += v[i] * v[i];
#pragma unroll
        for (int o = 32; o >= 1; o >>= 1) ss += __shfl_xor(ss, o);
        if (l == 0) red[wv] = ss;
        __syncthreads();
        float tot = red[0] + red[1] + red[2] + red[3];
        float rs = rsqrtf(tot * (1.0f / 4096.0f) + 1e-5f);
        __syncthreads();   // red is reused below
#pragma unroll
        for (int i = 0; i < 4; i++) {
            float4 wf = ((const float4*)Wg)[i * 256 + tid];
            v[4*i+0] = v[4*i+0] * rs * wf.x;
            v[4*i+1] = v[4*i+1] * rs * wf.y;
            v[4*i+2] = v[4*i+2] * rs * wf.z;
            v[4*i+3] = v[4*i+3] * rs * wf.w;
        }
    }
    float am = 0.f;
#pragma unroll
    for (int i = 0; i < 16; i++) am = fmaxf(am, fabsf(v[i]));
#pragma unroll
    for (int o = 32; o >= 1; o >>= 1) am = fmaxf(am, __shfl_xor(am, o));
    if (l == 0) red[wv] = am;
    __syncthreads();
    am = fmaxf(fmaxf(red[0], red[1]), fmaxf(red[2], red[3]));
    float s = fmaxf(am / 127.0f, 1e-8f);
    if (tid == 0) Sout[row] = s;
    unsigned short qb[16];
#pragma unroll
    for (int i = 0; i < 16; i++) {
        float q = rintf(v[i] / s);                 // true division: match jnp rounding
        q = fminf(fmaxf(q, -127.f), 127.f);
        qb[i] = f2bf(q);                           // integer <=127: exact in bf16
    }
    unsigned short* qr = Q + (size_t)row * 4096;
#pragma unroll
    for (int i = 0; i < 4; i++) {
        us4 o4 = { qb[4*i+0], qb[4*i+1], qb[4*i+2], qb[4*i+3] };
        ((us4*)qr)[i * 256 + tid] = o4;
    }
}

// ---------------------------------------------------------------------------
// bf16 GEMM: C[m][n] = sa[m]*sb[n] * sum_k A[m][k]*B[n][k]   (both K-major)
// 128x128 tile, BK=64, 4 waves (2x2), 16x16x32 MFMA, global_load_lds staging
// (m97 structure: linear LDS [128][64], width-16 async loads).
// ---------------------------------------------------------------------------
__global__ __launch_bounds__(256) void gemm_bf16(
    const unsigned short* __restrict__ A, const unsigned short* __restrict__ B,
    const float* __restrict__ sa, const float* __restrict__ sb,
    float* __restrict__ C, int M, int N, int K)
{
    __shared__ unsigned short As[128 * 64];
    __shared__ unsigned short Bs[128 * 64];
    int tid = threadIdx.x;
    int l = tid & 63, w = tid >> 6;
    int wr = w >> 1, wc = w & 1;
    int g = l >> 4, c = l & 15;
    int bn = blockIdx.x, bm = blockIdx.y;
    const unsigned short* Ab = A + (size_t)bm * 128 * K;
    const unsigned short* Bb = B + (size_t)bn * 128 * K;
    f4v acc[4][4] = {};
    int kt = K >> 6;
    for (int t = 0; t < kt; t++) {
        int k0 = t * 64;
#pragma unroll
        for (int i = 0; i < 4; i++) {
            int e = (i * 256 + tid) * 8;          // linear LDS element
            int r = e >> 6, cc = e & 63;
            gl2lds16(Ab + (size_t)r * K + k0 + cc, As + e);
            gl2lds16(Bb + (size_t)r * K + k0 + cc, Bs + e);
        }
        __syncthreads();                           // compiler drains vmcnt before barrier
#pragma unroll
        for (int kk = 0; kk < 2; kk++) {
            bh8 af[4], bf[4];
#pragma unroll
            for (int m = 0; m < 4; m++)
                af[m] = *(const bh8*)(As + (wr * 64 + m * 16 + c) * 64 + kk * 32 + g * 8);
#pragma unroll
            for (int n = 0; n < 4; n++)
                bf[n] = *(const bh8*)(Bs + (wc * 64 + n * 16 + c) * 64 + kk * 32 + g * 8);
#pragma unroll
            for (int m = 0; m < 4; m++)
#pragma unroll
                for (int n = 0; n < 4; n++)
                    acc[m][n] = __builtin_amdgcn_mfma_f32_16x16x32_bf16(af[m], bf[n], acc[m][n], 0, 0, 0);
        }
        __syncthreads();
    }
#pragma unroll
    for (int m = 0; m < 4; m++) {
#pragma unroll
        for (int j = 0; j < 4; j++) {
            int row = bm * 128 + wr * 64 + m * 16 + g * 4 + j;   // C/D: row=(l>>4)*4+reg
            float sr = sa[row];
#pragma unroll
            for (int n = 0; n < 4; n++) {
                int col = bn * 128 + wc * 64 + n * 16 + c;       // C/D: col=l&15
                C[(size_t)row * N + col] = acc[m][n][j] * sr * sb[col];
            }
        }
    }
}

// ---------------------------------------------------------------------------
// K path: int4 asym group quant (group=128 == one kv head) then RoPE, -> bf16.
// ---------------------------------------------------------------------------
__global__ __launch_bounds__(256) void k_quant_rope(
    const float* __restrict__ Kf, const int* __restrict__ pos,
    unsigned short* __restrict__ Kb)
{
    int wid = blockIdx.x * 4 + (threadIdx.x >> 6);
    int l = threadIdx.x & 63;
    int t = wid >> 3, kvh = wid & 7;
    const float* gp = Kf + (size_t)t * KVD + kvh * 128;
    float x1 = gp[l], x2 = gp[l + 64];
    float mn = fminf(x1, x2), mx = fmaxf(x1, x2);
#pragma unroll
    for (int o = 32; o >= 1; o >>= 1) {
        mn = fminf(mn, __shfl_xor(mn, o));
        mx = fmaxf(mx, __shfl_xor(mx, o));
    }
    float sc = fmaxf((mx - mn) / 15.0f, 1e-8f);
    float q1 = fminf(fmaxf(rintf((x1 - mn) / sc), 0.f), 15.f);
    float q2 = fminf(fmaxf(rintf((x2 - mn) / sc), 0.f), 15.f);
    x1 = q1 * sc + mn;
    x2 = q2 * sc + mn;
    float f = exp2f(-(float)l * 0.3114307588956902f);   // log2(1e6)/64
    float ang = (float)pos[t] * f;
    float cs = cosf(ang), sn = sinf(ang);
    unsigned short* op = Kb + (size_t)t * KVD + kvh * 128;
    op[l]      = f2bf(x1 * cs - x2 * sn);
    op[l + 64] = f2bf(x2 * cs + x1 * sn);
}

__global__ __launch_bounds__(256) void q_rope(
    const float* __restrict__ Qf, const int* __restrict__ pos,
    unsigned short* __restrict__ Qb)
{
    int wid = blockIdx.x * 4 + (threadIdx.x >> 6);
    int l = threadIdx.x & 63;
    int t = wid >> 5, h = wid & 31;
    const float* gp = Qf + (size_t)t * HID + h * 128;
    float x1 = gp[l], x2 = gp[l + 64];
    float f = exp2f(-(float)l * 0.3114307588956902f);
    float ang = (float)pos[t] * f;
    float cs = cosf(ang), sn = sinf(ang);
    unsigned short* op = Qb + (size_t)t * HID + h * 128;
    op[l]      = f2bf(x1 * cs - x2 * sn);
    op[l + 64] = f2bf(x2 * cs + x1 * sn);
}

__global__ __launch_bounds__(256) void v_quant(
    const float* __restrict__ Vf, unsigned short* __restrict__ Vbq)
{
    int wid = blockIdx.x * 4 + (threadIdx.x >> 6);
    int l = threadIdx.x & 63;
    int t = wid >> 3, kvh = wid & 7;
    const float* gp = Vf + (size_t)t * KVD + kvh * 128;
    float x1 = gp[l], x2 = gp[l + 64];
    float mn = fminf(x1, x2), mx = fmaxf(x1, x2);
#pragma unroll
    for (int o = 32; o >= 1; o >>= 1) {
        mn = fminf(mn, __shfl_xor(mn, o));
        mx = fmaxf(mx, __shfl_xor(mx, o));
    }
    float sc = fmaxf((mx - mn) / 15.0f, 1e-8f);
    float q1 = fminf(fmaxf(rintf((x1 - mn) / sc), 0.f), 15.f);
    float q2 = fminf(fmaxf(rintf((x2 - mn) / sc), 0.f), 15.f);
    unsigned short* op = Vbq + (size_t)t * KVD + kvh * 128;
    op[l]      = f2bf(q1 * sc + mn);
    op[l + 64] = f2bf(q2 * sc + mn);
}

// bf16 transpose [SQ][KVD] -> [KVD][SQ] via 64x64 LDS tiles
__global__ __launch_bounds__(256) void transpose_bf16(
    const unsigned short* __restrict__ in, unsigned short* __restrict__ out)
{
    __shared__ unsigned short tile[64][72];
    int bx = blockIdx.x;            // KVD/64
    int by = blockIdx.y;            // SQ/64
    int tid = threadIdx.x;
    int r = tid >> 3;
    int c8 = (tid & 7) * 8;
#pragma unroll
    for (int i = 0; i < 2; i++) {
        int rr = i * 32 + r;
        us8 v = *(const us8*)(in + (size_t)(by * 64 + rr) * KVD + bx * 64 + c8);
        *(us8*)(&tile[rr][c8]) = v;
    }
    __syncthreads();
#pragma unroll
    for (int i = 0; i < 2; i++) {
        int rr = i * 32 + r;
        us8 v;
#pragma unroll
        for (int j = 0; j < 8; j++) v[j] = tile[c8 + j][rr];
        *(us8*)(out + (size_t)(bx * 64 + rr) * SQ + by * 64 + c8) = v;
    }
}

// ---------------------------------------------------------------------------
// Causal GQA flash attention.  Block = (64-row Q tile, head); 4 waves x 16 rows.
// KVBLK=64.  K tile + V^T tile cooperatively staged in LDS (XOR chunk swizzle,
// 2-way conflict-free reads); next tile prefetched global->reg under compute
// (T14).  qt reversed so heavy blocks dispatch first.
// ---------------------------------------------------------------------------
__global__ __launch_bounds__(256) void attn_kernel(
    const unsigned short* __restrict__ Qb, const unsigned short* __restrict__ Kb,
    const unsigned short* __restrict__ Vbt, float* __restrict__ AO)
{
    const float SC  = 0.08838834764831845f;       // 1/sqrt(128)
    const float L2E = 1.44269504088896340736f;
    int qt = (int)gridDim.x - 1 - (int)blockIdx.x; // heavy tiles first
    int h = blockIdx.y;
    int kvh = h >> 2;                              // NREP=4, consecutive repeat
    int tid = threadIdx.x;
    int l = tid & 63, w = tid >> 6;
    int g = l >> 4, c = l & 15;
    __shared__ unsigned short Ks[64 * 128];        // K tile, chunk^(row&15) swizzle
    __shared__ unsigned short Vt[128 * 64];        // V^T tile, chunk^(row&7) swizzle
    __shared__ unsigned short Plds[4][16][72];
    int q0 = qt * 64 + w * 16;

    us8 kreg[4], vreg[4];
    auto stageK = [&](int kv0) {
#pragma unroll
        for (int i = 0; i < 4; i++) {
            int e = (i * 256 + tid) * 8;
            int r = e >> 7, cc = e & 127;
            kreg[i] = *(const us8*)(Kb + (size_t)(kv0 + r) * KVD + kvh * 128 + cc);
        }
    };
    auto stageV = [&](int kv0) {
#pragma unroll
        for (int i = 0; i < 4; i++) {
            int e = (i * 256 + tid) * 8;
            int r = e >> 6, cc = e & 63;
            vreg[i] = *(const us8*)(Vbt + (size_t)(kvh * 128 + r) * SQ + kv0 + cc);
        }
    };
    auto writeKV = [&]() {
#pragma unroll
        for (int i = 0; i < 4; i++) {
            int e = (i * 256 + tid) * 8;
            int rk = e >> 7, chk = (e >> 3) & 15;
            *(us8*)(Ks + rk * 128 + ((chk ^ (rk & 15)) << 3)) = kreg[i];
            int rv = e >> 6, chv = (e >> 3) & 7;
            *(us8*)(Vt + rv * 64 + ((chv ^ (rv & 7)) << 3)) = vreg[i];
        }
    };

    stageK(0); stageV(0);
    writeKV();

    bh8 qf[4];
    const unsigned short* qrow = Qb + (size_t)(q0 + c) * HID + h * 128;
#pragma unroll
    for (int kk = 0; kk < 4; kk++) qf[kk] = *(const bh8*)(qrow + kk * 32 + g * 8);

    f4v acc[8] = {};
    float mrun[4] = { -1e30f, -1e30f, -1e30f, -1e30f };
    float lrun[4] = { 0.f, 0.f, 0.f, 0.f };
    __syncthreads();

    for (int t = 0; t <= qt; t++) {
        int kv0 = t * 64;
        if (t < qt) { stageK(kv0 + 64); stageV(kv0 + 64); }   // prefetch under compute
        // S = Q K^T  (16 q-rows x 64 keys per wave), K from LDS
        f4v sf[4];
#pragma unroll
        for (int n = 0; n < 4; n++) {
            f4v a = {};
            int row = n * 16 + c;
#pragma unroll
            for (int kk = 0; kk < 4; kk++) {
                bh8 kf = *(const bh8*)(Ks + row * 128 + (((kk * 4 + g) ^ (row & 15)) << 3));
                a = __builtin_amdgcn_mfma_f32_16x16x32_bf16(qf[kk], kf, a, 0, 0, 0);
            }
            sf[n] = a;
        }
        // scale + causal mask + row max (C layout: row=g*4+j, col=n*16+c)
        float pmax[4] = { -1e30f, -1e30f, -1e30f, -1e30f };
#pragma unroll
        for (int n = 0; n < 4; n++) {
            int col = kv0 + n * 16 + c;
#pragma unroll
            for (int j = 0; j < 4; j++) {
                int row = q0 + g * 4 + j;
                float sv = (col <= row) ? sf[n][j] * SC : -1e30f;
                sf[n][j] = sv;
                pmax[j] = fmaxf(pmax[j], sv);
            }
        }
        float alpha[4];
#pragma unroll
        for (int j = 0; j < 4; j++) {
            float m = pmax[j];
            m = fmaxf(m, __shfl_xor(m, 1));
            m = fmaxf(m, __shfl_xor(m, 2));
            m = fmaxf(m, __shfl_xor(m, 4));
            m = fmaxf(m, __shfl_xor(m, 8));
            float mnew = fmaxf(mrun[j], m);
            alpha[j] = exp2f((mrun[j] - mnew) * L2E);
            mrun[j] = mnew;
            lrun[j] *= alpha[j];
        }
        float rsum[4] = { 0.f, 0.f, 0.f, 0.f };
#pragma unroll
        for (int n = 0; n < 4; n++) {
#pragma unroll
            for (int j = 0; j < 4; j++) {
                float pv = exp2f((sf[n][j] - mrun[j]) * L2E);
                sf[n][j] = pv;
                rsum[j] += pv;
            }
        }
#pragma unroll
        for (int j = 0; j < 4; j++) {
            float r = rsum[j];
            r += __shfl_xor(r, 1);
            r += __shfl_xor(r, 2);
            r += __shfl_xor(r, 4);
            r += __shfl_xor(r, 8);
            lrun[j] += r;
        }
#pragma unroll
        for (int n = 0; n < 8; n++) {
#pragma unroll
            for (int j = 0; j < 4; j++) acc[n][j] *= alpha[j];
        }
        // P: C-layout -> bf16 -> LDS -> A-layout (wave-local, no barrier needed)
#pragma unroll
        for (int n = 0; n < 4; n++) {
#pragma unroll
            for (int j = 0; j < 4; j++)
                Plds[w][g * 4 + j][n * 16 + c] = f2bf(sf[n][j]);
        }
#pragma unroll
        for (int kk = 0; kk < 2; kk++) {
            bh8 pa = *(const bh8*)(&Plds[w][c][kk * 32 + g * 8]);
#pragma unroll
            for (int n = 0; n < 8; n++) {
                int row = n * 16 + c;
                bh8 vf = *(const bh8*)(Vt + row * 64 + (((kk * 4 + g) ^ (row & 7)) << 3));
                acc[n] = __builtin_amdgcn_mfma_f32_16x16x32_bf16(pa, vf, acc[n], 0, 0, 0);
            }
        }
        if (t < qt) {
            __syncthreads();      // all waves done reading Ks/Vt
            writeKV();            // compiler waits vmcnt on kreg/vreg here
            __syncthreads();      // tile t+1 visible
        }
    }
#pragma unroll
    for (int j = 0; j < 4; j++) {
        int row = q0 + g * 4 + j;
        float inv = 1.0f / lrun[j];
#pragma unroll
        for (int n = 0; n < 8; n++)
            AO[(size_t)row * HID + h * 128 + n * 16 + c] = acc[n][j] * inv;
    }
}

// ---------------------------------------------------------------------------
extern "C" void kernel_launch(void* const* d_in, const int* in_sizes, int n_in,
                              void* d_out, int out_size, void* d_ws, size_t ws_size,
                              hipStream_t stream)
{
    const float* x   = (const float*)d_in[0];
    const int*   pos = (const int*)d_in[1];
    const float* rw  = (const float*)d_in[2];
    const float* Wq  = (const float*)d_in[3];
    const float* Wk  = (const float*)d_in[4];
    const float* Wv  = (const float*)d_in[5];
    const float* Wo  = (const float*)d_in[6];
    float* out = (float*)d_out;

    char* p = (char*)d_ws;
    auto alloc = [&](size_t bytes) -> void* {
        void* r = (void*)p;
        p += (bytes + 255) & ~(size_t)255;
        return r;
    };
    unsigned short* xq   = (unsigned short*)alloc((size_t)SQ * HID * 2);
    float*          sx   = (float*)alloc(SQ * 4);
    unsigned short* wqq  = (unsigned short*)alloc((size_t)HID * HID * 2);
    unsigned short* wkq  = (unsigned short*)alloc((size_t)KVD * HID * 2);
    unsigned short* wvq  = (unsigned short*)alloc((size_t)KVD * HID * 2);
    unsigned short* woq  = (unsigned short*)alloc((size_t)HID * HID * 2);
    float*          swq  = (float*)alloc(HID * 4);
    float*          swk  = (float*)alloc(KVD * 4);
    float*          swv  = (float*)alloc(KVD * 4);
    float*          swo  = (float*)alloc(HID * 4);
    float*          Qf   = (float*)alloc((size_t)SQ * HID * 4);     // reused as AO
    float*          Kf   = (float*)alloc((size_t)SQ * KVD * 4);     // Kf+Vf contiguous:
    float*          Vf   = (float*)alloc((size_t)SQ * KVD * 4);     //  reused as attq
    unsigned short* Qb   = (unsigned short*)alloc((size_t)SQ * HID * 2);
    unsigned short* Kb   = (unsigned short*)alloc((size_t)SQ * KVD * 2);
    unsigned short* Vbq  = (unsigned short*)alloc((size_t)SQ * KVD * 2);
    unsigned short* Vbt  = (unsigned short*)alloc((size_t)SQ * KVD * 2);
    float*          sa   = (float*)alloc(SQ * 4);

    size_t need = (size_t)(p - (char*)d_ws);
    if (ws_size < need) {
        // sentinel: absmax ~3.4e38 tells us ws was too small
        hipMemsetAsync(d_out, 0x7f, 4, stream);
        return;
    }
    float*          AO   = Qf;                       // Qf dead after q_rope
    unsigned short* attq = (unsigned short*)Kf;      // Kf/Vf dead after quant+rope
    // 1) weight fake-quant (per output channel)
    rowquant_kernel<<<HID, 256, 0, stream>>>(Wq, nullptr, wqq, swq, 0);
    rowquant_kernel<<<KVD, 256, 0, stream>>>(Wk, nullptr, wkq, swk, 0);
    rowquant_kernel<<<KVD, 256, 0, stream>>>(Wv, nullptr, wvq, swv, 0);
    rowquant_kernel<<<HID, 256, 0, stream>>>(Wo, nullptr, woq, swo, 0);
    // 2) rmsnorm + per-token int8 fake-quant
    rowquant_kernel<<<SQ, 256, 0, stream>>>(x, rw, xq, sx, 1);
    // 3) Q/K/V projections (exact integer math in bf16 MFMA)
    gemm_bf16<<<dim3(HID / 128, SQ / 128), 256, 0, stream>>>(xq, wqq, sx, swq, Qf, SQ, HID, HID);
    gemm_bf16<<<dim3(KVD / 128, SQ / 128), 256, 0, stream>>>(xq, wkq, sx, swk, Kf, SQ, KVD, HID);
    gemm_bf16<<<dim3(KVD / 128, SQ / 128), 256, 0, stream>>>(xq, wvq, sx, swv, Vf, SQ, KVD, HID);
    // 4) K int4 quant + RoPE ; Q RoPE ; V int4 quant + transpose
    k_quant_rope<<<SQ * NKVH / 4, 256, 0, stream>>>(Kf, pos, Kb);
    q_rope<<<SQ * NHEAD / 4, 256, 0, stream>>>(Qf, pos, Qb);
    v_quant<<<SQ * NKVH / 4, 256, 0, stream>>>(Vf, Vbq);
    transpose_bf16<<<dim3(KVD / 64, SQ / 64), 256, 0, stream>>>(Vbq, Vbt);
    // 5) causal GQA flash attention
    attn_kernel<<<dim3(SQ / 64, NHEAD), 256, 0, stream>>>(Qb, Kb, Vbt, AO);
    // 6) per-token int8 fake-quant of attention output + O projection
    rowquant_kernel<<<SQ, 256, 0, stream>>>(AO, nullptr, attq, sa, 0);
    gemm_bf16<<<dim3(HID / 128, SQ / 128), 256, 0, stream>>>(attq, woq, sa, swo, out, SQ, HID, HID);
}

// Round 3
// 515.802 us; speedup vs baseline: 1.8549x; 1.2514x over previous
//
#include <hip/hip_runtime.h>

// ---------------------------------------------------------------------------
// QMixtralAttention: rmsnorm -> int8 fake-quant -> QKV proj (exact int-in-bf16
// MFMA, merged N=6144) -> int4 KV-cache quant -> RoPE -> causal GQA flash
// attention (swapped-operand MFMA, in-lane softmax) -> int8 fake-quant -> O proj.
// ---------------------------------------------------------------------------

#define SQ   2048
#define HID  4096
#define NHEAD 32
#define HDIM 128
#define NKVH 8
#define KVD  1024   // NKVH*HDIM
#define QKVN 6144   // HID + 2*KVD

typedef __attribute__((ext_vector_type(8))) short          bh8;   // 8 x bf16 bits (MFMA operand)
typedef __attribute__((ext_vector_type(8))) unsigned short us8;
typedef __attribute__((ext_vector_type(4))) unsigned short us4;
typedef __attribute__((ext_vector_type(4))) float          f4v;

__device__ __forceinline__ unsigned short f2bf(float f) {
    unsigned u = __float_as_uint(f);
    u += 0x7fffu + ((u >> 16) & 1u);          // RNE
    return (unsigned short)(u >> 16);
}

__device__ __forceinline__ unsigned cvtpk_bf16(float a, float b) {
    unsigned r;
    asm("v_cvt_pk_bf16_f32 %0, %1, %2" : "=v"(r) : "v"(a), "v"(b));
    return r;   // lo = bf16(a), hi = bf16(b)  (RNE)
}

// async global -> LDS, 16B per lane (m97 pattern)
__device__ __forceinline__ void gl2lds16(const unsigned short* g, unsigned short* l) {
    __builtin_amdgcn_global_load_lds(
        (const __attribute__((address_space(1))) unsigned int*)g,
        (__attribute__((address_space(3))) unsigned int*)l, 16, 0, 0);
}

// ---------------------------------------------------------------------------
// Per-row (4096-wide) symmetric int8 fake-quant, optional fused RMSNorm.
// ---------------------------------------------------------------------------
__global__ __launch_bounds__(256) void rowquant_kernel(
    const float* __restrict__ X, const float* __restrict__ Wg,
    unsigned short* __restrict__ Q, float* __restrict__ Sout, int do_rms)
{
    int row = blockIdx.x;
    int tid = threadIdx.x;
    int l = tid & 63, wv = tid >> 6;
    const float* xr = X + (size_t)row * 4096;
    float v[16];
#pragma unroll
    for (int i = 0; i < 4; i++) {
        float4 f = ((const float4*)xr)[i * 256 + tid];
        v[4*i+0] = f.x; v[4*i+1] = f.y; v[4*i+2] = f.z; v[4*i+3] = f.w;
    }
    __shared__ float red[4];
    if (do_rms) {
        float ss = 0.f;
#pragma unroll
        for (int i = 0; i < 16; i++) ss += v[i] * v[i];
#pragma unroll
        for (int o = 32; o >= 1; o >>= 1) ss += __shfl_xor(ss, o);
        if (l == 0) red[wv] = ss;
        __syncthreads();
        float tot = red[0] + red[1] + red[2] + red[3];
        float rs = rsqrtf(tot * (1.0f / 4096.0f) + 1e-5f);
        __syncthreads();   // red is reused below
#pragma unroll
        for (int i = 0; i < 4; i++) {
            float4 wf = ((const float4*)Wg)[i * 256 + tid];
            v[4*i+0] = v[4*i+0] * rs * wf.x;
            v[4*i+1] = v[4*i+1] * rs * wf.y;
            v[4*i+2] = v[4*i+2] * rs * wf.z;
            v[4*i+3] = v[4*i+3] * rs * wf.w;
        }
    }
    float am = 0.f;
#pragma unroll
    for (int i = 0; i < 16; i++) am = fmaxf(am, fabsf(v[i]));
#pragma unroll
    for (int o = 32; o >= 1; o >>= 1) am = fmaxf(am, __shfl_xor(am, o));
    if (l == 0) red[wv] = am;
    __syncthreads();
    am = fmaxf(fmaxf(red[0], red[1]), fmaxf(red[2], red[3]));
    float s = fmaxf(am / 127.0f, 1e-8f);
    if (tid == 0) Sout[row] = s;
    unsigned short qb[16];
#pragma unroll
    for (int i = 0; i < 16; i++) {
        float q = rintf(v[i] / s);                 // true division: match jnp rounding
        q = fminf(fmaxf(q, -127.f), 127.f);
        qb[i] = f2bf(q);                           // integer <=127: exact in bf16
    }
    unsigned short* qr = Q + (size_t)row * 4096;
#pragma unroll
    for (int i = 0; i < 4; i++) {
        us4 o4 = { qb[4*i+0], qb[4*i+1], qb[4*i+2], qb[4*i+3] };
        ((us4*)qr)[i * 256 + tid] = o4;
    }
}

// ---------------------------------------------------------------------------
// bf16 GEMM: C[m][n] = sa[m]*sb[n] * sum_k A[m][k]*B[n][k]   (both K-major)
// 128x128 tile, BK=64, 4 waves (2x2), 16x16x32 MFMA, global_load_lds staging.
// ---------------------------------------------------------------------------
__global__ __launch_bounds__(256) void gemm_bf16(
    const unsigned short* __restrict__ A, const unsigned short* __restrict__ B,
    const float* __restrict__ sa, const float* __restrict__ sb,
    float* __restrict__ C, int M, int N, int K)
{
    __shared__ unsigned short As[128 * 64];
    __shared__ unsigned short Bs[128 * 64];
    int tid = threadIdx.x;
    int l = tid & 63, w = tid >> 6;
    int wr = w >> 1, wc = w & 1;
    int g = l >> 4, c = l & 15;
    int bn = blockIdx.x, bm = blockIdx.y;
    const unsigned short* Ab = A + (size_t)bm * 128 * K;
    const unsigned short* Bb = B + (size_t)bn * 128 * K;
    f4v acc[4][4] = {};
    int kt = K >> 6;
    for (int t = 0; t < kt; t++) {
        int k0 = t * 64;
#pragma unroll
        for (int i = 0; i < 4; i++) {
            int e = (i * 256 + tid) * 8;          // linear LDS element
            int r = e >> 6, cc = e & 63;
            gl2lds16(Ab + (size_t)r * K + k0 + cc, As + e);
            gl2lds16(Bb + (size_t)r * K + k0 + cc, Bs + e);
        }
        __syncthreads();                           // compiler drains vmcnt before barrier
#pragma unroll
        for (int kk = 0; kk < 2; kk++) {
            bh8 af[4], bf[4];
#pragma unroll
            for (int m = 0; m < 4; m++)
                af[m] = *(const bh8*)(As + (wr * 64 + m * 16 + c) * 64 + kk * 32 + g * 8);
#pragma unroll
            for (int n = 0; n < 4; n++)
                bf[n] = *(const bh8*)(Bs + (wc * 64 + n * 16 + c) * 64 + kk * 32 + g * 8);
#pragma unroll
            for (int m = 0; m < 4; m++)
#pragma unroll
                for (int n = 0; n < 4; n++)
                    acc[m][n] = __builtin_amdgcn_mfma_f32_16x16x32_bf16(af[m], bf[n], acc[m][n], 0, 0, 0);
        }
        __syncthreads();
    }
#pragma unroll
    for (int m = 0; m < 4; m++) {
#pragma unroll
        for (int j = 0; j < 4; j++) {
            int row = bm * 128 + wr * 64 + m * 16 + g * 4 + j;   // C/D: row=(l>>4)*4+reg
            float sr = sa[row];
#pragma unroll
            for (int n = 0; n < 4; n++) {
                int col = bn * 128 + wc * 64 + n * 16 + c;       // C/D: col=l&15
                C[(size_t)row * N + col] = acc[m][n][j] * sr * sb[col];
            }
        }
    }
}

// ---------------------------------------------------------------------------
// K path: int4 asym group quant (group=128 == one kv head) then RoPE, -> bf16.
// rs = row stride of the (strided) source view.
// ---------------------------------------------------------------------------
__global__ __launch_bounds__(256) void k_quant_rope(
    const float* __restrict__ Kf, const int* __restrict__ pos,
    unsigned short* __restrict__ Kb, int rs)
{
    int wid = blockIdx.x * 4 + (threadIdx.x >> 6);
    int l = threadIdx.x & 63;
    int t = wid >> 3, kvh = wid & 7;
    const float* gp = Kf + (size_t)t * rs + kvh * 128;
    float x1 = gp[l], x2 = gp[l + 64];
    float mn = fminf(x1, x2), mx = fmaxf(x1, x2);
#pragma unroll
    for (int o = 32; o >= 1; o >>= 1) {
        mn = fminf(mn, __shfl_xor(mn, o));
        mx = fmaxf(mx, __shfl_xor(mx, o));
    }
    float sc = fmaxf((mx - mn) / 15.0f, 1e-8f);
    float q1 = fminf(fmaxf(rintf((x1 - mn) / sc), 0.f), 15.f);
    float q2 = fminf(fmaxf(rintf((x2 - mn) / sc), 0.f), 15.f);
    x1 = q1 * sc + mn;
    x2 = q2 * sc + mn;
    float f = exp2f(-(float)l * 0.3114307588956902f);   // log2(1e6)/64
    float ang = (float)pos[t] * f;
    float cs = cosf(ang), sn = sinf(ang);
    unsigned short* op = Kb + (size_t)t * KVD + kvh * 128;
    op[l]      = f2bf(x1 * cs - x2 * sn);
    op[l + 64] = f2bf(x2 * cs + x1 * sn);
}

// Q RoPE; also folds softmax scale 1/sqrt(128) * log2(e) into Q (single
// rounding to bf16 -- no extra error vs unscaled).
__global__ __launch_bounds__(256) void q_rope(
    const float* __restrict__ Qf, const int* __restrict__ pos,
    unsigned short* __restrict__ Qb, int rs)
{
    const float QSCL = (float)(0.08838834764831845 * 1.4426950408889634);
    int wid = blockIdx.x * 4 + (threadIdx.x >> 6);
    int l = threadIdx.x & 63;
    int t = wid >> 5, h = wid & 31;
    const float* gp = Qf + (size_t)t * rs + h * 128;
    float x1 = gp[l], x2 = gp[l + 64];
    float f = exp2f(-(float)l * 0.3114307588956902f);
    float ang = (float)pos[t] * f;
    float cs = cosf(ang), sn = sinf(ang);
    unsigned short* op = Qb + (size_t)t * HID + h * 128;
    op[l]      = f2bf((x1 * cs - x2 * sn) * QSCL);
    op[l + 64] = f2bf((x2 * cs + x1 * sn) * QSCL);
}

__global__ __launch_bounds__(256) void v_quant(
    const float* __restrict__ Vf, unsigned short* __restrict__ Vbq, int rs)
{
    int wid = blockIdx.x * 4 + (threadIdx.x >> 6);
    int l = threadIdx.x & 63;
    int t = wid >> 3, kvh = wid & 7;
    const float* gp = Vf + (size_t)t * rs + kvh * 128;
    float x1 = gp[l], x2 = gp[l + 64];
    float mn = fminf(x1, x2), mx = fmaxf(x1, x2);
#pragma unroll
    for (int o = 32; o >= 1; o >>= 1) {
        mn = fminf(mn, __shfl_xor(mn, o));
        mx = fmaxf(mx, __shfl_xor(mx, o));
    }
    float sc = fmaxf((mx - mn) / 15.0f, 1e-8f);
    float q1 = fminf(fmaxf(rintf((x1 - mn) / sc), 0.f), 15.f);
    float q2 = fminf(fmaxf(rintf((x2 - mn) / sc), 0.f), 15.f);
    unsigned short* op = Vbq + (size_t)t * KVD + kvh * 128;
    op[l]      = f2bf(q1 * sc + mn);
    op[l + 64] = f2bf(q2 * sc + mn);
}

// bf16 transpose [SQ][KVD] -> [KVD][SQ] via 64x64 LDS tiles
__global__ __launch_bounds__(256) void transpose_bf16(
    const unsigned short* __restrict__ in, unsigned short* __restrict__ out)
{
    __shared__ unsigned short tile[64][72];
    int bx = blockIdx.x;            // KVD/64
    int by = blockIdx.y;            // SQ/64
    int tid = threadIdx.x;
    int r = tid >> 3;
    int c8 = (tid & 7) * 8;
#pragma unroll
    for (int i = 0; i < 2; i++) {
        int rr = i * 32 + r;
        us8 v = *(const us8*)(in + (size_t)(by * 64 + rr) * KVD + bx * 64 + c8);
        *(us8*)(&tile[rr][c8]) = v;
    }
    __syncthreads();
#pragma unroll
    for (int i = 0; i < 2; i++) {
        int rr = i * 32 + r;
        us8 v;
#pragma unroll
        for (int j = 0; j < 8; j++) v[j] = tile[c8 + j][rr];
        *(us8*)(out + (size_t)(bx * 64 + rr) * SQ + by * 64 + c8) = v;
    }
}

// ---------------------------------------------------------------------------
// Causal GQA flash attention, swapped-operand MFMA.
// Block = (64-row Q tile, head); 4 waves x 16 q-rows.  KVBLK=64.
// QK^T computed as mfma(K,Q) -> S[key][q], q = lane&15: softmax row-reduce is
// in-lane (15 fmax/add) + 2 shuffles.  PV as mfma(V^T, P) -> O[d][q].
// Q pre-scaled by 1/sqrt(128)*log2e.  Defer-max (T13, THR=8 log2-units).
// K/V^T tiles staged in LDS; next tile prefetched global->reg under compute.
// ---------------------------------------------------------------------------
__global__ __launch_bounds__(256) void attn_kernel(
    const unsigned short* __restrict__ Qb, const unsigned short* __restrict__ Kb,
    const unsigned short* __restrict__ Vbt, float* __restrict__ AO)
{
    int qt = (int)gridDim.x - 1 - (int)blockIdx.x; // heavy tiles first
    int h = blockIdx.y;
    int kvh = h >> 2;                              // NREP=4, consecutive repeat
    int tid = threadIdx.x;
    int l = tid & 63, w = tid >> 6;
    int g = l >> 4, c = l & 15;
    __shared__ unsigned short Ks[64 * 128];        // K tile, chunk^(row&15) swizzle
    __shared__ unsigned short Vt[128 * 64];        // V^T tile, chunk^(row&7) swizzle
    __shared__ unsigned short Plds[4][16][80];     // P rows (per q), pad 80
    int q0 = qt * 64 + w * 16;
    int qrow = q0 + c;                             // this lane's q-row

    us8 kreg[4], vreg[4];
    auto stageK = [&](int kv0) {
#pragma unroll
        for (int i = 0; i < 4; i++) {
            int e = (i * 256 + tid) * 8;
            int r = e >> 7, cc = e & 127;
            kreg[i] = *(const us8*)(Kb + (size_t)(kv0 + r) * KVD + kvh * 128 + cc);
        }
    };
    auto stageV = [&](int kv0) {
#pragma unroll
        for (int i = 0; i < 4; i++) {
            int e = (i * 256 + tid) * 8;
            int r = e >> 6, cc = e & 63;
            vreg[i] = *(const us8*)(Vbt + (size_t)(kvh * 128 + r) * SQ + kv0 + cc);
        }
    };
    auto writeKV = [&]() {
#pragma unroll
        for (int i = 0; i < 4; i++) {
            int e = (i * 256 + tid) * 8;
            int rk = e >> 7, chk = (e >> 3) & 15;
            *(us8*)(Ks + rk * 128 + ((chk ^ (rk & 15)) << 3)) = kreg[i];
            int rv = e >> 6, chv = (e >> 3) & 7;
            *(us8*)(Vt + rv * 64 + ((chv ^ (rv & 7)) << 3)) = vreg[i];
        }
    };

    stageK(0); stageV(0);
    writeKV();

    bh8 qf[4];
    const unsigned short* qrp = Qb + (size_t)qrow * HID + h * 128;
#pragma unroll
    for (int kk = 0; kk < 4; kk++) qf[kk] = *(const bh8*)(qrp + kk * 32 + g * 8);

    f4v acc[8] = {};                 // O[d = n*16+g*4+j][qrow], unnormalized
    float mrun = -1e30f, lrun = 0.f;
    __syncthreads();

    for (int t = 0; t <= qt; t++) {
        int kv0 = t * 64;
        if (t < qt) { stageK(kv0 + 64); stageV(kv0 + 64); }   // prefetch under compute
        // S = K Q^T  (swapped): sf[n][j] = S[key kv0+n*16+g*4+j][qrow]
        f4v sf[4];
        __builtin_amdgcn_s_setprio(1);
#pragma unroll
        for (int n = 0; n < 4; n++) {
            f4v a = {};
            int row = n * 16 + c;
#pragma unroll
            for (int kk = 0; kk < 4; kk++) {
                bh8 kf = *(const bh8*)(Ks + row * 128 + (((kk * 4 + g) ^ (row & 15)) << 3));
                a = __builtin_amdgcn_mfma_f32_16x16x32_bf16(kf, qf[kk], a, 0, 0, 0);
            }
            sf[n] = a;
        }
        __builtin_amdgcn_s_setprio(0);
        if (t == qt) {                 // causal mask: diagonal tile only
#pragma unroll
            for (int n = 0; n < 4; n++)
#pragma unroll
                for (int j = 0; j < 4; j++)
                    if (kv0 + n * 16 + g * 4 + j > qrow) sf[n][j] = -1e30f;
        }
        // in-lane row max + cross-g reduce
        float pmax = sf[0][0];
#pragma unroll
        for (int n = 0; n < 4; n++)
#pragma unroll
            for (int j = 0; j < 4; j++) pmax = fmaxf(pmax, sf[n][j]);
        pmax = fmaxf(pmax, __shfl_xor(pmax, 16));
        pmax = fmaxf(pmax, __shfl_xor(pmax, 32));
        if (__any(pmax - mrun > 8.0f)) {           // defer-max (T13)
            float mnew = fmaxf(mrun, pmax);
            float alpha = exp2f(mrun - mnew);
            mrun = mnew;
            lrun *= alpha;
#pragma unroll
            for (int n = 0; n < 8; n++) acc[n] *= alpha;
        }
        // P = exp2(s - m) in place; in-lane sum + cross-g reduce
        float rs = 0.f;
#pragma unroll
        for (int n = 0; n < 4; n++)
#pragma unroll
            for (int j = 0; j < 4; j++) {
                float p = exp2f(sf[n][j] - mrun);
                sf[n][j] = p;
                rs += p;
            }
        rs += __shfl_xor(rs, 16);
        rs += __shfl_xor(rs, 32);
        lrun += rs;
        // pack P row -> bf16 pairs -> LDS (keys n*16+g*4+{0..3} at row qrow)
#pragma unroll
        for (int n = 0; n < 4; n++) {
            uint2 u;
            u.x = cvtpk_bf16(sf[n][0], sf[n][1]);
            u.y = cvtpk_bf16(sf[n][2], sf[n][3]);
            *(uint2*)(&Plds[w][c][n * 16 + g * 4]) = u;
        }
        // PV (swapped): acc[n] += mfma(V^T rows, P rows)
        __builtin_amdgcn_s_setprio(1);
#pragma unroll
        for (int kk = 0; kk < 2; kk++) {
            bh8 pb = *(const bh8*)(&Plds[w][c][kk * 32 + g * 8]);
#pragma unroll
            for (int n = 0; n < 8; n++) {
                int row = n * 16 + c;
                bh8 vf = *(const bh8*)(Vt + row * 64 + (((kk * 4 + g) ^ (row & 7)) << 3));
                acc[n] = __builtin_amdgcn_mfma_f32_16x16x32_bf16(vf, pb, acc[n], 0, 0, 0);
            }
        }
        __builtin_amdgcn_s_setprio(0);
        if (t < qt) {
            __syncthreads();      // all waves done reading Ks/Vt
            writeKV();            // compiler waits vmcnt on kreg/vreg here
            __syncthreads();      // tile t+1 visible
        }
    }
    // epilogue: lane holds O[d][qrow]; contiguous d -> float4 stores
    float inv = 1.0f / lrun;
#pragma unroll
    for (int n = 0; n < 8; n++) {
        f4v o = acc[n] * inv;
        *(f4v*)(AO + (size_t)qrow * HID + h * 128 + n * 16 + g * 4) = o;
    }
}

// ---------------------------------------------------------------------------
extern "C" void kernel_launch(void* const* d_in, const int* in_sizes, int n_in,
                              void* d_out, int out_size, void* d_ws, size_t ws_size,
                              hipStream_t stream)
{
    const float* x   = (const float*)d_in[0];
    const int*   pos = (const int*)d_in[1];
    const float* rw  = (const float*)d_in[2];
    const float* Wq  = (const float*)d_in[3];
    const float* Wk  = (const float*)d_in[4];
    const float* Wv  = (const float*)d_in[5];
    const float* Wo  = (const float*)d_in[6];
    float* out = (float*)d_out;

    char* p = (char*)d_ws;
    auto alloc = [&](size_t bytes) -> void* {
        void* r = (void*)p;
        p += (bytes + 255) & ~(size_t)255;
        return r;
    };
    unsigned short* xq    = (unsigned short*)alloc((size_t)SQ * HID * 2);
    float*          sx    = (float*)alloc(SQ * 4);
    unsigned short* wqkv  = (unsigned short*)alloc((size_t)QKVN * HID * 2);
    unsigned short* woq   = (unsigned short*)alloc((size_t)HID * HID * 2);
    float*          swqkv = (float*)alloc(QKVN * 4);
    float*          swo   = (float*)alloc(HID * 4);
    float*          QKVf  = (float*)alloc((size_t)SQ * QKVN * 4);  // reused: AO, attq
    unsigned short* Qb    = (unsigned short*)alloc((size_t)SQ * HID * 2);
    unsigned short* Kb    = (unsigned short*)alloc((size_t)SQ * KVD * 2);
    unsigned short* Vbq   = (unsigned short*)alloc((size_t)SQ * KVD * 2);
    unsigned short* Vbt   = (unsigned short*)alloc((size_t)SQ * KVD * 2);
    float*          sa    = (float*)alloc(SQ * 4);

    size_t need = (size_t)(p - (char*)d_ws);
    if (ws_size < need) {
        // sentinel: absmax ~3.4e38 tells us ws was too small
        hipMemsetAsync(d_out, 0x7f, 4, stream);
        return;
    }
    float*          AO   = QKVf;                                   // QKV consumed before attn
    unsigned short* attq = (unsigned short*)(QKVf + (size_t)SQ * HID);
    // 1) weight fake-quant (per output channel) into merged QKV buffer + Wo
    rowquant_kernel<<<HID, 256, 0, stream>>>(Wq, nullptr, wqkv,                       swqkv,        0);
    rowquant_kernel<<<KVD, 256, 0, stream>>>(Wk, nullptr, wqkv + (size_t)HID * HID,   swqkv + HID,  0);
    rowquant_kernel<<<KVD, 256, 0, stream>>>(Wv, nullptr, wqkv + (size_t)(HID + KVD) * HID, swqkv + HID + KVD, 0);
    rowquant_kernel<<<HID, 256, 0, stream>>>(Wo, nullptr, woq, swo, 0);
    // 2) rmsnorm + per-token int8 fake-quant
    rowquant_kernel<<<SQ, 256, 0, stream>>>(x, rw, xq, sx, 1);
    // 3) merged QKV projection (exact integer math in bf16 MFMA)
    gemm_bf16<<<dim3(QKVN / 128, SQ / 128), 256, 0, stream>>>(xq, wqkv, sx, swqkv, QKVf, SQ, QKVN, HID);
    // 4) K int4 quant + RoPE ; Q RoPE (pre-scaled) ; V int4 quant + transpose
    k_quant_rope<<<SQ * NKVH / 4, 256, 0, stream>>>(QKVf + HID, pos, Kb, QKVN);
    q_rope<<<SQ * NHEAD / 4, 256, 0, stream>>>(QKVf, pos, Qb, QKVN);
    v_quant<<<SQ * NKVH / 4, 256, 0, stream>>>(QKVf + HID + KVD, Vbq, QKVN);
    transpose_bf16<<<dim3(KVD / 64, SQ / 64), 256, 0, stream>>>(Vbq, Vbt);
    // 5) causal GQA flash attention (swapped-operand)
    attn_kernel<<<dim3(SQ / 64, NHEAD), 256, 0, stream>>>(Qb, Kb, Vbt, AO);
    // 6) per-token int8 fake-quant of attention output + O projection
    rowquant_kernel<<<SQ, 256, 0, stream>>>(AO, nullptr, attq, sa, 0);
    gemm_bf16<<<dim3(HID / 128, SQ / 128), 256, 0, stream>>>(attq, woq, sa, swo, out, SQ, HID, HID);
}

// Round 4
// 484.872 us; speedup vs baseline: 1.9733x; 1.0638x over previous
//
#include <hip/hip_runtime.h>

// ---------------------------------------------------------------------------
// QMixtralAttention: rmsnorm -> int8 fake-quant -> QKV proj (exact int-in-bf16
// MFMA, merged N=6144, 256x256 8-phase schedule) -> int4 KV quant -> RoPE ->
// causal GQA flash attention (swapped-operand MFMA) -> int8 fake-quant -> O proj.
// ---------------------------------------------------------------------------

#define SQ   2048
#define HID  4096
#define NHEAD 32
#define HDIM 128
#define NKVH 8
#define KVD  1024   // NKVH*HDIM
#define QKVN 6144   // HID + 2*KVD

typedef __attribute__((ext_vector_type(8))) short          bh8;   // 8 x bf16 bits (MFMA operand)
typedef __attribute__((ext_vector_type(8))) unsigned short us8;
typedef __attribute__((ext_vector_type(4))) unsigned short us4;
typedef __attribute__((ext_vector_type(4))) float          f4v;

__device__ __forceinline__ unsigned short f2bf(float f) {
    unsigned u = __float_as_uint(f);
    u += 0x7fffu + ((u >> 16) & 1u);          // RNE
    return (unsigned short)(u >> 16);
}

__device__ __forceinline__ unsigned cvtpk_bf16(float a, float b) {
    unsigned r;
    asm("v_cvt_pk_bf16_f32 %0, %1, %2" : "=v"(r) : "v"(a), "v"(b));
    return r;   // lo = bf16(a), hi = bf16(b)  (RNE)
}

// async global -> LDS, 16B per lane (m97 pattern)
__device__ __forceinline__ void gl2lds16(const unsigned short* g, unsigned short* l) {
    __builtin_amdgcn_global_load_lds(
        (const __attribute__((address_space(1))) unsigned int*)g,
        (__attribute__((address_space(3))) unsigned int*)l, 16, 0, 0);
}

// ---------------------------------------------------------------------------
// Per-row (4096-wide) symmetric int8 fake-quant, optional fused RMSNorm.
// ---------------------------------------------------------------------------
__global__ __launch_bounds__(256) void rowquant_kernel(
    const float* __restrict__ X, const float* __restrict__ Wg,
    unsigned short* __restrict__ Q, float* __restrict__ Sout, int do_rms)
{
    int row = blockIdx.x;
    int tid = threadIdx.x;
    int l = tid & 63, wv = tid >> 6;
    const float* xr = X + (size_t)row * 4096;
    float v[16];
#pragma unroll
    for (int i = 0; i < 4; i++) {
        float4 f = ((const float4*)xr)[i * 256 + tid];
        v[4*i+0] = f.x; v[4*i+1] = f.y; v[4*i+2] = f.z; v[4*i+3] = f.w;
    }
    __shared__ float red[4];
    if (do_rms) {
        float ss = 0.f;
#pragma unroll
        for (int i = 0; i < 16; i++) ss += v[i] * v[i];
#pragma unroll
        for (int o = 32; o >= 1; o >>= 1) ss += __shfl_xor(ss, o);
        if (l == 0) red[wv] = ss;
        __syncthreads();
        float tot = red[0] + red[1] + red[2] + red[3];
        float rs = rsqrtf(tot * (1.0f / 4096.0f) + 1e-5f);
        __syncthreads();   // red is reused below
#pragma unroll
        for (int i = 0; i < 4; i++) {
            float4 wf = ((const float4*)Wg)[i * 256 + tid];
            v[4*i+0] = v[4*i+0] * rs * wf.x;
            v[4*i+1] = v[4*i+1] * rs * wf.y;
            v[4*i+2] = v[4*i+2] * rs * wf.z;
            v[4*i+3] = v[4*i+3] * rs * wf.w;
        }
    }
    float am = 0.f;
#pragma unroll
    for (int i = 0; i < 16; i++) am = fmaxf(am, fabsf(v[i]));
#pragma unroll
    for (int o = 32; o >= 1; o >>= 1) am = fmaxf(am, __shfl_xor(am, o));
    if (l == 0) red[wv] = am;
    __syncthreads();
    am = fmaxf(fmaxf(red[0], red[1]), fmaxf(red[2], red[3]));
    float s = fmaxf(am / 127.0f, 1e-8f);
    if (tid == 0) Sout[row] = s;
    unsigned short qb[16];
#pragma unroll
    for (int i = 0; i < 16; i++) {
        float q = rintf(v[i] / s);                 // true division: match jnp rounding
        q = fminf(fmaxf(q, -127.f), 127.f);
        qb[i] = f2bf(q);                           // integer <=127: exact in bf16
    }
    unsigned short* qr = Q + (size_t)row * 4096;
#pragma unroll
    for (int i = 0; i < 4; i++) {
        us4 o4 = { qb[4*i+0], qb[4*i+1], qb[4*i+2], qb[4*i+3] };
        ((us4*)qr)[i * 256 + tid] = o4;
    }
}

// ---------------------------------------------------------------------------
// bf16 GEMM, 256x256 tile, BK=64, 8 waves (2Mx4N), 8-phase-style schedule:
// per phase { ds_read quadrant | stage 1 half-tile (2x global_load_lds,
// pre-swizzled source) | vmcnt(4) | s_barrier | lgkmcnt(0) | 16 MFMA | bar }.
// LDS chunk^(row&7) swizzle kills ds_read_b128 bank conflicts (T2);
// counted vmcnt keeps 2 half-tiles in flight across barriers (T3+T4);
// setprio around MFMA clusters (T5); bijective XCD swizzle (T1).
// C[m][n] = sa[m]*sb[n] * sum_k A[m][k]*B[n][k]   (both K-major)
// ---------------------------------------------------------------------------
__global__ __launch_bounds__(512, 2) void gemm256(
    const unsigned short* __restrict__ A, const unsigned short* __restrict__ B,
    const float* __restrict__ sa, const float* __restrict__ sb,
    float* __restrict__ C, int M, int N, int K, int NBM)
{
    __shared__ unsigned short As[2 * 16384];   // 2 buf x 256 rows x 64 cols
    __shared__ unsigned short Bs[2 * 16384];
    int tid = threadIdx.x;
    int l = tid & 63;
    int wid = tid >> 6;
    int wr = wid >> 2, wc = wid & 3;           // 2 x 4 wave grid
    int g = l >> 4, c = l & 15;
    // bijective XCD swizzle (grid is a multiple of 8 for all our shapes)
    int wg = blockIdx.x;
    int cpx = (int)gridDim.x >> 3;
    int swz = (wg & 7) * cpx + (wg >> 3);
    int bm = swz % NBM, bn = swz / NBM;
    const unsigned short* Ab = A + (size_t)bm * 256 * K;
    const unsigned short* Bb = B + (size_t)bn * 256 * K;

    // stage one half-tile (128 rows x 64 cols) of one operand into dstbuf.
    // LDS dest is linear (wave-uniform base + lane*16); the chunk^(row&7)
    // swizzle is applied by permuting the per-lane GLOBAL source (rule 21).
    auto stage = [&](const unsigned short* Gb, unsigned short* Ls, int dstbuf,
                     int hf, int tt) {
#pragma unroll
        for (int r = 0; r < 2; r++) {
            int e = (r * 512 + tid) * 8;       // element offset within half
            int row = e >> 6;                  // 0..127
            int chunk = (e >> 3) & 7;
            gl2lds16(Gb + (size_t)(hf * 128 + row) * K + tt * 64 + ((chunk ^ (row & 7)) << 3),
                     Ls + dstbuf * 16384 + hf * 8192 + e);
        }
    };
    bh8 af[4][2], bf0[2][2], bf1[2][2];
    auto LDA = [&](int buf, int mq) {
#pragma unroll
        for (int fm = 0; fm < 4; fm++)
#pragma unroll
            for (int kk = 0; kk < 2; kk++) {
                int row = mq * 128 + wr * 64 + fm * 16 + c;
                af[fm][kk] = *(const bh8*)(As + buf * 16384 + row * 64 +
                                           ((((kk << 2) + g) ^ (row & 7)) << 3));
            }
    };
    auto LDB = [&](bh8 (&bf)[2][2], int buf, int nq) {
#pragma unroll
        for (int fn = 0; fn < 2; fn++)
#pragma unroll
            for (int kk = 0; kk < 2; kk++) {
                int row = nq * 128 + wc * 32 + fn * 16 + c;
                bf[fn][kk] = *(const bh8*)(Bs + buf * 16384 + row * 64 +
                                           ((((kk << 2) + g) ^ (row & 7)) << 3));
            }
    };
    f4v a00[4][2] = {}, a01[4][2] = {}, a10[4][2] = {}, a11[4][2] = {};
    auto MQ = [&](f4v (&acc)[4][2], bh8 (&bb)[2][2]) {
#pragma unroll
        for (int kk = 0; kk < 2; kk++)
#pragma unroll
            for (int fm = 0; fm < 4; fm++)
#pragma unroll
                for (int fn = 0; fn < 2; fn++)
                    acc[fm][fn] = __builtin_amdgcn_mfma_f32_16x16x32_bf16(
                        af[fm][kk], bb[fn][kk], acc[fm][fn], 0, 0, 0);
    };

#define GBAR asm volatile("s_barrier" ::: "memory")
#define VMC4 asm volatile("s_waitcnt vmcnt(4)" ::: "memory")
#define VMC0 asm volatile("s_waitcnt vmcnt(0)" ::: "memory")
#define LGK0 asm volatile("s_waitcnt lgkmcnt(0)" ::: "memory")
#define PHASE_TAIL(ACC, BF)                    \
    GBAR; LGK0;                                \
    __builtin_amdgcn_sched_barrier(0);         \
    __builtin_amdgcn_s_setprio(1);             \
    MQ(ACC, BF);                               \
    __builtin_amdgcn_s_setprio(0);             \
    GBAR;

    // prologue: tile 0 -> buf0 (stage order A0,B0,B1,A1 matches read order)
    stage(Ab, As, 0, 0, 0); stage(Bb, Bs, 0, 0, 0);
    stage(Bb, Bs, 0, 1, 0); stage(Ab, As, 0, 1, 0);
    VMC0; GBAR;
    int nt = K >> 6;
    for (int t = 0; t < nt - 1; t++) {
        int buf = t & 1, nb = buf ^ 1;
        // P1: quadrant (mq0,nq0); stage A0(t+1)
        LDA(buf, 0); LDB(bf0, buf, 0);
        stage(Ab, As, nb, 0, t + 1);
        VMC4; PHASE_TAIL(a00, bf0);
        // P2: (mq0,nq1); stage B0(t+1)
        LDB(bf1, buf, 1);
        stage(Bb, Bs, nb, 0, t + 1);
        VMC4; PHASE_TAIL(a01, bf1);
        // P3: (mq1,nq0); stage B1(t+1)
        LDA(buf, 1);
        stage(Bb, Bs, nb, 1, t + 1);
        VMC4; PHASE_TAIL(a10, bf0);
        // P4: (mq1,nq1); stage A1(t+1)
        stage(Ab, As, nb, 1, t + 1);
        VMC4; PHASE_TAIL(a11, bf1);
    }
    {   // peeled last tile: no staging, single drain
        int buf = (nt - 1) & 1;
        VMC0; GBAR;
        LDA(buf, 0); LDB(bf0, buf, 0); LDB(bf1, buf, 1);
        MQ(a00, bf0); MQ(a01, bf1);
        LDA(buf, 1);
        MQ(a10, bf0); MQ(a11, bf1);
    }
    // epilogue: C[row][col] = acc * sa[row] * sb[col]
    auto store = [&](f4v (&acc)[4][2], int mq, int nq) {
#pragma unroll
        for (int fm = 0; fm < 4; fm++)
#pragma unroll
            for (int j = 0; j < 4; j++) {
                int row = bm * 256 + mq * 128 + wr * 64 + fm * 16 + g * 4 + j;
                float sr = sa[row];
#pragma unroll
                for (int fn = 0; fn < 2; fn++) {
                    int col = bn * 256 + nq * 128 + wc * 32 + fn * 16 + c;
                    C[(size_t)row * N + col] = acc[fm][fn][j] * sr * sb[col];
                }
            }
    };
    store(a00, 0, 0); store(a01, 0, 1); store(a10, 1, 0); store(a11, 1, 1);
#undef GBAR
#undef VMC4
#undef VMC0
#undef LGK0
#undef PHASE_TAIL
}

// ---------------------------------------------------------------------------
// K path: int4 asym group quant (group=128 == one kv head) then RoPE, -> bf16.
// rs = row stride of the (strided) source view.
// ---------------------------------------------------------------------------
__global__ __launch_bounds__(256) void k_quant_rope(
    const float* __restrict__ Kf, const int* __restrict__ pos,
    unsigned short* __restrict__ Kb, int rs)
{
    int wid = blockIdx.x * 4 + (threadIdx.x >> 6);
    int l = threadIdx.x & 63;
    int t = wid >> 3, kvh = wid & 7;
    const float* gp = Kf + (size_t)t * rs + kvh * 128;
    float x1 = gp[l], x2 = gp[l + 64];
    float mn = fminf(x1, x2), mx = fmaxf(x1, x2);
#pragma unroll
    for (int o = 32; o >= 1; o >>= 1) {
        mn = fminf(mn, __shfl_xor(mn, o));
        mx = fmaxf(mx, __shfl_xor(mx, o));
    }
    float sc = fmaxf((mx - mn) / 15.0f, 1e-8f);
    float q1 = fminf(fmaxf(rintf((x1 - mn) / sc), 0.f), 15.f);
    float q2 = fminf(fmaxf(rintf((x2 - mn) / sc), 0.f), 15.f);
    x1 = q1 * sc + mn;
    x2 = q2 * sc + mn;
    float f = exp2f(-(float)l * 0.3114307588956902f);   // log2(1e6)/64
    float ang = (float)pos[t] * f;
    float cs = cosf(ang), sn = sinf(ang);
    unsigned short* op = Kb + (size_t)t * KVD + kvh * 128;
    op[l]      = f2bf(x1 * cs - x2 * sn);
    op[l + 64] = f2bf(x2 * cs + x1 * sn);
}

// Q RoPE; also folds softmax scale 1/sqrt(128) * log2(e) into Q (single
// rounding to bf16 -- no extra error vs unscaled).
__global__ __launch_bounds__(256) void q_rope(
    const float* __restrict__ Qf, const int* __restrict__ pos,
    unsigned short* __restrict__ Qb, int rs)
{
    const float QSCL = (float)(0.08838834764831845 * 1.4426950408889634);
    int wid = blockIdx.x * 4 + (threadIdx.x >> 6);
    int l = threadIdx.x & 63;
    int t = wid >> 5, h = wid & 31;
    const float* gp = Qf + (size_t)t * rs + h * 128;
    float x1 = gp[l], x2 = gp[l + 64];
    float f = exp2f(-(float)l * 0.3114307588956902f);
    float ang = (float)pos[t] * f;
    float cs = cosf(ang), sn = sinf(ang);
    unsigned short* op = Qb + (size_t)t * HID + h * 128;
    op[l]      = f2bf((x1 * cs - x2 * sn) * QSCL);
    op[l + 64] = f2bf((x2 * cs + x1 * sn) * QSCL);
}

__global__ __launch_bounds__(256) void v_quant(
    const float* __restrict__ Vf, unsigned short* __restrict__ Vbq, int rs)
{
    int wid = blockIdx.x * 4 + (threadIdx.x >> 6);
    int l = threadIdx.x & 63;
    int t = wid >> 3, kvh = wid & 7;
    const float* gp = Vf + (size_t)t * rs + kvh * 128;
    float x1 = gp[l], x2 = gp[l + 64];
    float mn = fminf(x1, x2), mx = fmaxf(x1, x2);
#pragma unroll
    for (int o = 32; o >= 1; o >>= 1) {
        mn = fminf(mn, __shfl_xor(mn, o));
        mx = fmaxf(mx, __shfl_xor(mx, o));
    }
    float sc = fmaxf((mx - mn) / 15.0f, 1e-8f);
    float q1 = fminf(fmaxf(rintf((x1 - mn) / sc), 0.f), 15.f);
    float q2 = fminf(fmaxf(rintf((x2 - mn) / sc), 0.f), 15.f);
    unsigned short* op = Vbq + (size_t)t * KVD + kvh * 128;
    op[l]      = f2bf(q1 * sc + mn);
    op[l + 64] = f2bf(q2 * sc + mn);
}

// bf16 transpose [SQ][KVD] -> [KVD][SQ] via 64x64 LDS tiles
__global__ __launch_bounds__(256) void transpose_bf16(
    const unsigned short* __restrict__ in, unsigned short* __restrict__ out)
{
    __shared__ unsigned short tile[64][72];
    int bx = blockIdx.x;            // KVD/64
    int by = blockIdx.y;            // SQ/64
    int tid = threadIdx.x;
    int r = tid >> 3;
    int c8 = (tid & 7) * 8;
#pragma unroll
    for (int i = 0; i < 2; i++) {
        int rr = i * 32 + r;
        us8 v = *(const us8*)(in + (size_t)(by * 64 + rr) * KVD + bx * 64 + c8);
        *(us8*)(&tile[rr][c8]) = v;
    }
    __syncthreads();
#pragma unroll
    for (int i = 0; i < 2; i++) {
        int rr = i * 32 + r;
        us8 v;
#pragma unroll
        for (int j = 0; j < 8; j++) v[j] = tile[c8 + j][rr];
        *(us8*)(out + (size_t)(bx * 64 + rr) * SQ + by * 64 + c8) = v;
    }
}

// ---------------------------------------------------------------------------
// Causal GQA flash attention, swapped-operand MFMA.
// Block = (64-row Q tile, head); 4 waves x 16 q-rows.  KVBLK=64.
// QK^T computed as mfma(K,Q) -> S[key][q], q = lane&15: softmax row-reduce is
// in-lane (15 fmax/add) + 2 shuffles.  PV as mfma(V^T, P) -> O[d][q].
// Q pre-scaled by 1/sqrt(128)*log2e.  Defer-max (T13, THR=8 log2-units).
// K/V^T tiles staged in LDS; next tile prefetched global->reg under compute.
// ---------------------------------------------------------------------------
__global__ __launch_bounds__(256) void attn_kernel(
    const unsigned short* __restrict__ Qb, const unsigned short* __restrict__ Kb,
    const unsigned short* __restrict__ Vbt, float* __restrict__ AO)
{
    int qt = (int)gridDim.x - 1 - (int)blockIdx.x; // heavy tiles first
    int h = blockIdx.y;
    int kvh = h >> 2;                              // NREP=4, consecutive repeat
    int tid = threadIdx.x;
    int l = tid & 63, w = tid >> 6;
    int g = l >> 4, c = l & 15;
    __shared__ unsigned short Ks[64 * 128];        // K tile, chunk^(row&15) swizzle
    __shared__ unsigned short Vt[128 * 64];        // V^T tile, chunk^(row&7) swizzle
    __shared__ unsigned short Plds[4][16][80];     // P rows (per q), pad 80
    int q0 = qt * 64 + w * 16;
    int qrow = q0 + c;                             // this lane's q-row

    us8 kreg[4], vreg[4];
    auto stageK = [&](int kv0) {
#pragma unroll
        for (int i = 0; i < 4; i++) {
            int e = (i * 256 + tid) * 8;
            int r = e >> 7, cc = e & 127;
            kreg[i] = *(const us8*)(Kb + (size_t)(kv0 + r) * KVD + kvh * 128 + cc);
        }
    };
    auto stageV = [&](int kv0) {
#pragma unroll
        for (int i = 0; i < 4; i++) {
            int e = (i * 256 + tid) * 8;
            int r = e >> 6, cc = e & 63;
            vreg[i] = *(const us8*)(Vbt + (size_t)(kvh * 128 + r) * SQ + kv0 + cc);
        }
    };
    auto writeKV = [&]() {
#pragma unroll
        for (int i = 0; i < 4; i++) {
            int e = (i * 256 + tid) * 8;
            int rk = e >> 7, chk = (e >> 3) & 15;
            *(us8*)(Ks + rk * 128 + ((chk ^ (rk & 15)) << 3)) = kreg[i];
            int rv = e >> 6, chv = (e >> 3) & 7;
            *(us8*)(Vt + rv * 64 + ((chv ^ (rv & 7)) << 3)) = vreg[i];
        }
    };

    stageK(0); stageV(0);
    writeKV();

    bh8 qf[4];
    const unsigned short* qrp = Qb + (size_t)qrow * HID + h * 128;
#pragma unroll
    for (int kk = 0; kk < 4; kk++) qf[kk] = *(const bh8*)(qrp + kk * 32 + g * 8);

    f4v acc[8] = {};                 // O[d = n*16+g*4+j][qrow], unnormalized
    float mrun = -1e30f, lrun = 0.f;
    __syncthreads();

    for (int t = 0; t <= qt; t++) {
        int kv0 = t * 64;
        if (t < qt) { stageK(kv0 + 64); stageV(kv0 + 64); }   // prefetch under compute
        // S = K Q^T  (swapped): sf[n][j] = S[key kv0+n*16+g*4+j][qrow]
        f4v sf[4];
        __builtin_amdgcn_s_setprio(1);
#pragma unroll
        for (int n = 0; n < 4; n++) {
            f4v a = {};
            int row = n * 16 + c;
#pragma unroll
            for (int kk = 0; kk < 4; kk++) {
                bh8 kf = *(const bh8*)(Ks + row * 128 + (((kk * 4 + g) ^ (row & 15)) << 3));
                a = __builtin_amdgcn_mfma_f32_16x16x32_bf16(kf, qf[kk], a, 0, 0, 0);
            }
            sf[n] = a;
        }
        __builtin_amdgcn_s_setprio(0);
        if (t == qt) {                 // causal mask: diagonal tile only
#pragma unroll
            for (int n = 0; n < 4; n++)
#pragma unroll
                for (int j = 0; j < 4; j++)
                    if (kv0 + n * 16 + g * 4 + j > qrow) sf[n][j] = -1e30f;
        }
        // in-lane row max + cross-g reduce
        float pmax = sf[0][0];
#pragma unroll
        for (int n = 0; n < 4; n++)
#pragma unroll
            for (int j = 0; j < 4; j++) pmax = fmaxf(pmax, sf[n][j]);
        pmax = fmaxf(pmax, __shfl_xor(pmax, 16));
        pmax = fmaxf(pmax, __shfl_xor(pmax, 32));
        if (__any(pmax - mrun > 8.0f)) {           // defer-max (T13)
            float mnew = fmaxf(mrun, pmax);
            float alpha = exp2f(mrun - mnew);
            mrun = mnew;
            lrun *= alpha;
#pragma unroll
            for (int n = 0; n < 8; n++) acc[n] *= alpha;
        }
        // P = exp2(s - m) in place; in-lane sum + cross-g reduce
        float rs = 0.f;
#pragma unroll
        for (int n = 0; n < 4; n++)
#pragma unroll
            for (int j = 0; j < 4; j++) {
                float p = exp2f(sf[n][j] - mrun);
                sf[n][j] = p;
                rs += p;
            }
        rs += __shfl_xor(rs, 16);
        rs += __shfl_xor(rs, 32);
        lrun += rs;
        // pack P row -> bf16 pairs -> LDS (keys n*16+g*4+{0..3} at row qrow)
#pragma unroll
        for (int n = 0; n < 4; n++) {
            uint2 u;
            u.x = cvtpk_bf16(sf[n][0], sf[n][1]);
            u.y = cvtpk_bf16(sf[n][2], sf[n][3]);
            *(uint2*)(&Plds[w][c][n * 16 + g * 4]) = u;
        }
        // PV (swapped): acc[n] += mfma(V^T rows, P rows)
        __builtin_amdgcn_s_setprio(1);
#pragma unroll
        for (int kk = 0; kk < 2; kk++) {
            bh8 pb = *(const bh8*)(&Plds[w][c][kk * 32 + g * 8]);
#pragma unroll
            for (int n = 0; n < 8; n++) {
                int row = n * 16 + c;
                bh8 vf = *(const bh8*)(Vt + row * 64 + (((kk * 4 + g) ^ (row & 7)) << 3));
                acc[n] = __builtin_amdgcn_mfma_f32_16x16x32_bf16(vf, pb, acc[n], 0, 0, 0);
            }
        }
        __builtin_amdgcn_s_setprio(0);
        if (t < qt) {
            __syncthreads();      // all waves done reading Ks/Vt
            writeKV();            // compiler waits vmcnt on kreg/vreg here
            __syncthreads();      // tile t+1 visible
        }
    }
    // epilogue: lane holds O[d][qrow]; contiguous d -> float4 stores
    float inv = 1.0f / lrun;
#pragma unroll
    for (int n = 0; n < 8; n++) {
        f4v o = acc[n] * inv;
        *(f4v*)(AO + (size_t)qrow * HID + h * 128 + n * 16 + g * 4) = o;
    }
}

// ---------------------------------------------------------------------------
extern "C" void kernel_launch(void* const* d_in, const int* in_sizes, int n_in,
                              void* d_out, int out_size, void* d_ws, size_t ws_size,
                              hipStream_t stream)
{
    const float* x   = (const float*)d_in[0];
    const int*   pos = (const int*)d_in[1];
    const float* rw  = (const float*)d_in[2];
    const float* Wq  = (const float*)d_in[3];
    const float* Wk  = (const float*)d_in[4];
    const float* Wv  = (const float*)d_in[5];
    const float* Wo  = (const float*)d_in[6];
    float* out = (float*)d_out;

    char* p = (char*)d_ws;
    auto alloc = [&](size_t bytes) -> void* {
        void* r = (void*)p;
        p += (bytes + 255) & ~(size_t)255;
        return r;
    };
    unsigned short* xq    = (unsigned short*)alloc((size_t)SQ * HID * 2);
    float*          sx    = (float*)alloc(SQ * 4);
    unsigned short* wqkv  = (unsigned short*)alloc((size_t)QKVN * HID * 2);
    unsigned short* woq   = (unsigned short*)alloc((size_t)HID * HID * 2);
    float*          swqkv = (float*)alloc(QKVN * 4);
    float*          swo   = (float*)alloc(HID * 4);
    float*          QKVf  = (float*)alloc((size_t)SQ * QKVN * 4);  // reused: AO, attq
    unsigned short* Qb    = (unsigned short*)alloc((size_t)SQ * HID * 2);
    unsigned short* Kb    = (unsigned short*)alloc((size_t)SQ * KVD * 2);
    unsigned short* Vbq   = (unsigned short*)alloc((size_t)SQ * KVD * 2);
    unsigned short* Vbt   = (unsigned short*)alloc((size_t)SQ * KVD * 2);
    float*          sa    = (float*)alloc(SQ * 4);

    size_t need = (size_t)(p - (char*)d_ws);
    if (ws_size < need) {
        // sentinel: absmax ~3.4e38 tells us ws was too small
        hipMemsetAsync(d_out, 0x7f, 4, stream);
        return;
    }
    float*          AO   = QKVf;                                   // QKV consumed before attn
    unsigned short* attq = (unsigned short*)(QKVf + (size_t)SQ * HID);
    // 1) weight fake-quant (per output channel) into merged QKV buffer + Wo
    rowquant_kernel<<<HID, 256, 0, stream>>>(Wq, nullptr, wqkv,                       swqkv,        0);
    rowquant_kernel<<<KVD, 256, 0, stream>>>(Wk, nullptr, wqkv + (size_t)HID * HID,   swqkv + HID,  0);
    rowquant_kernel<<<KVD, 256, 0, stream>>>(Wv, nullptr, wqkv + (size_t)(HID + KVD) * HID, swqkv + HID + KVD, 0);
    rowquant_kernel<<<HID, 256, 0, stream>>>(Wo, nullptr, woq, swo, 0);
    // 2) rmsnorm + per-token int8 fake-quant
    rowquant_kernel<<<SQ, 256, 0, stream>>>(x, rw, xq, sx, 1);
    // 3) merged QKV projection (exact integer math in bf16 MFMA)
    gemm256<<<dim3((SQ / 256) * (QKVN / 256)), 512, 0, stream>>>(
        xq, wqkv, sx, swqkv, QKVf, SQ, QKVN, HID, SQ / 256);
    // 4) K int4 quant + RoPE ; Q RoPE (pre-scaled) ; V int4 quant + transpose
    k_quant_rope<<<SQ * NKVH / 4, 256, 0, stream>>>(QKVf + HID, pos, Kb, QKVN);
    q_rope<<<SQ * NHEAD / 4, 256, 0, stream>>>(QKVf, pos, Qb, QKVN);
    v_quant<<<SQ * NKVH / 4, 256, 0, stream>>>(QKVf + HID + KVD, Vbq, QKVN);
    transpose_bf16<<<dim3(KVD / 64, SQ / 64), 256, 0, stream>>>(Vbq, Vbt);
    // 5) causal GQA flash attention (swapped-operand)
    attn_kernel<<<dim3(SQ / 64, NHEAD), 256, 0, stream>>>(Qb, Kb, Vbt, AO);
    // 6) per-token int8 fake-quant of attention output + O projection
    rowquant_kernel<<<SQ, 256, 0, stream>>>(AO, nullptr, attq, sa, 0);
    gemm256<<<dim3((SQ / 256) * (HID / 256)), 512, 0, stream>>>(
        attq, woq, sa, swo, out, SQ, HID, HID, SQ / 256);
}

// Round 5
// 413.940 us; speedup vs baseline: 2.3114x; 1.1714x over previous
//
#include <hip/hip_runtime.h>

// ---------------------------------------------------------------------------
// QMixtralAttention: rmsnorm -> int8 fake-quant -> QKV proj (exact int-in-bf16
// MFMA, merged N=6144, 256x256 8-phase schedule) -> int4 KV quant -> RoPE ->
// causal GQA flash attention (swapped-operand MFMA, QBLK=128) -> int8 -> O proj.
// ---------------------------------------------------------------------------

#define SQ   2048
#define HID  4096
#define NHEAD 32
#define HDIM 128
#define NKVH 8
#define KVD  1024   // NKVH*HDIM
#define QKVN 6144   // HID + 2*KVD

typedef __attribute__((ext_vector_type(8))) short          bh8;   // 8 x bf16 bits (MFMA operand)
typedef __attribute__((ext_vector_type(8))) unsigned short us8;
typedef __attribute__((ext_vector_type(4))) unsigned short us4;
typedef __attribute__((ext_vector_type(4))) float          f4v;

__device__ __forceinline__ unsigned short f2bf(float f) {
    unsigned u = __float_as_uint(f);
    u += 0x7fffu + ((u >> 16) & 1u);          // RNE
    return (unsigned short)(u >> 16);
}

__device__ __forceinline__ unsigned cvtpk_bf16(float a, float b) {
    unsigned r;
    asm("v_cvt_pk_bf16_f32 %0, %1, %2" : "=v"(r) : "v"(a), "v"(b));
    return r;   // lo = bf16(a), hi = bf16(b)  (RNE)
}

// async global -> LDS, 16B per lane (m97 pattern)
__device__ __forceinline__ void gl2lds16(const unsigned short* g, unsigned short* l) {
    __builtin_amdgcn_global_load_lds(
        (const __attribute__((address_space(1))) unsigned int*)g,
        (__attribute__((address_space(3))) unsigned int*)l, 16, 0, 0);
}

// ---------------------------------------------------------------------------
// Shared per-row (4096-wide) symmetric int8 fake-quant body.
// ---------------------------------------------------------------------------
__device__ __forceinline__ void rq_body(const float* __restrict__ xr, float v[16],
                                        unsigned short* __restrict__ dst,
                                        float* __restrict__ sout,
                                        float* red, int tid, int l, int wv)
{
    float am = 0.f;
#pragma unroll
    for (int i = 0; i < 16; i++) am = fmaxf(am, fabsf(v[i]));
#pragma unroll
    for (int o = 32; o >= 1; o >>= 1) am = fmaxf(am, __shfl_xor(am, o));
    if (l == 0) red[wv] = am;
    __syncthreads();
    am = fmaxf(fmaxf(red[0], red[1]), fmaxf(red[2], red[3]));
    float s = fmaxf(am / 127.0f, 1e-8f);
    if (tid == 0) *sout = s;
    unsigned short qb[16];
#pragma unroll
    for (int i = 0; i < 16; i++) {
        float q = rintf(v[i] / s);                 // true division: match jnp rounding
        q = fminf(fmaxf(q, -127.f), 127.f);
        qb[i] = f2bf(q);                           // integer <=127: exact in bf16
    }
#pragma unroll
    for (int i = 0; i < 4; i++) {
        us4 o4 = { qb[4*i+0], qb[4*i+1], qb[4*i+2], qb[4*i+3] };
        ((us4*)dst)[i * 256 + tid] = o4;
    }
}

// Per-row int8 fake-quant with optional fused RMSNorm (hidden states / attn out)
__global__ __launch_bounds__(256) void rowquant_kernel(
    const float* __restrict__ X, const float* __restrict__ Wg,
    unsigned short* __restrict__ Q, float* __restrict__ Sout, int do_rms)
{
    int row = blockIdx.x;
    int tid = threadIdx.x;
    int l = tid & 63, wv = tid >> 6;
    const float* xr = X + (size_t)row * 4096;
    float v[16];
#pragma unroll
    for (int i = 0; i < 4; i++) {
        float4 f = ((const float4*)xr)[i * 256 + tid];
        v[4*i+0] = f.x; v[4*i+1] = f.y; v[4*i+2] = f.z; v[4*i+3] = f.w;
    }
    __shared__ float red[4];
    if (do_rms) {
        float ss = 0.f;
#pragma unroll
        for (int i = 0; i < 16; i++) ss += v[i] * v[i];
#pragma unroll
        for (int o = 32; o >= 1; o >>= 1) ss += __shfl_xor(ss, o);
        if (l == 0) red[wv] = ss;
        __syncthreads();
        float tot = red[0] + red[1] + red[2] + red[3];
        float rs = rsqrtf(tot * (1.0f / 4096.0f) + 1e-5f);
        __syncthreads();   // red is reused below
#pragma unroll
        for (int i = 0; i < 4; i++) {
            float4 wf = ((const float4*)Wg)[i * 256 + tid];
            v[4*i+0] = v[4*i+0] * rs * wf.x;
            v[4*i+1] = v[4*i+1] * rs * wf.y;
            v[4*i+2] = v[4*i+2] * rs * wf.z;
            v[4*i+3] = v[4*i+3] * rs * wf.w;
        }
    }
    rq_body(xr, v, Q + (size_t)row * 4096, Sout + row, red, tid, l, wv);
}

// All 4 weight matrices fake-quantized in ONE dispatch (10240 rows).
__global__ __launch_bounds__(256) void wquant4(
    const float* __restrict__ Wq, const float* __restrict__ Wk,
    const float* __restrict__ Wv, const float* __restrict__ Wo,
    unsigned short* __restrict__ wqkv, unsigned short* __restrict__ woq,
    float* __restrict__ swqkv, float* __restrict__ swo)
{
    int row = blockIdx.x;
    const float* src; unsigned short* dst; float* sout;
    if (row < HID)          { src = Wq + (size_t)row * HID;             dst = wqkv + (size_t)row * HID; sout = swqkv + row; }
    else if (row < HID+KVD) { src = Wk + (size_t)(row - HID) * HID;     dst = wqkv + (size_t)row * HID; sout = swqkv + row; }
    else if (row < QKVN)    { src = Wv + (size_t)(row - HID - KVD) * HID; dst = wqkv + (size_t)row * HID; sout = swqkv + row; }
    else { int r = row - QKVN; src = Wo + (size_t)r * HID;              dst = woq + (size_t)r * HID;  sout = swo + r; }
    int tid = threadIdx.x;
    int l = tid & 63, wv = tid >> 6;
    float v[16];
#pragma unroll
    for (int i = 0; i < 4; i++) {
        float4 f = ((const float4*)src)[i * 256 + tid];
        v[4*i+0] = f.x; v[4*i+1] = f.y; v[4*i+2] = f.z; v[4*i+3] = f.w;
    }
    __shared__ float red[4];
    rq_body(src, v, dst, sout, red, tid, l, wv);
}

// ---------------------------------------------------------------------------
// bf16 GEMM, 256x256 tile, BK=64, 8 waves (2Mx4N), 8-phase-style schedule.
// (unchanged from round 3 -- T1..T5 applied)
// ---------------------------------------------------------------------------
__global__ __launch_bounds__(512, 2) void gemm256(
    const unsigned short* __restrict__ A, const unsigned short* __restrict__ B,
    const float* __restrict__ sa, const float* __restrict__ sb,
    float* __restrict__ C, int M, int N, int K, int NBM)
{
    __shared__ unsigned short As[2 * 16384];   // 2 buf x 256 rows x 64 cols
    __shared__ unsigned short Bs[2 * 16384];
    int tid = threadIdx.x;
    int l = tid & 63;
    int wid = tid >> 6;
    int wr = wid >> 2, wc = wid & 3;           // 2 x 4 wave grid
    int g = l >> 4, c = l & 15;
    int wg = blockIdx.x;
    int cpx = (int)gridDim.x >> 3;
    int swz = (wg & 7) * cpx + (wg >> 3);
    int bm = swz % NBM, bn = swz / NBM;
    const unsigned short* Ab = A + (size_t)bm * 256 * K;
    const unsigned short* Bb = B + (size_t)bn * 256 * K;

    auto stage = [&](const unsigned short* Gb, unsigned short* Ls, int dstbuf,
                     int hf, int tt) {
#pragma unroll
        for (int r = 0; r < 2; r++) {
            int e = (r * 512 + tid) * 8;       // element offset within half
            int row = e >> 6;                  // 0..127
            int chunk = (e >> 3) & 7;
            gl2lds16(Gb + (size_t)(hf * 128 + row) * K + tt * 64 + ((chunk ^ (row & 7)) << 3),
                     Ls + dstbuf * 16384 + hf * 8192 + e);
        }
    };
    bh8 af[4][2], bf0[2][2], bf1[2][2];
    auto LDA = [&](int buf, int mq) {
#pragma unroll
        for (int fm = 0; fm < 4; fm++)
#pragma unroll
            for (int kk = 0; kk < 2; kk++) {
                int row = mq * 128 + wr * 64 + fm * 16 + c;
                af[fm][kk] = *(const bh8*)(As + buf * 16384 + row * 64 +
                                           ((((kk << 2) + g) ^ (row & 7)) << 3));
            }
    };
    auto LDB = [&](bh8 (&bf)[2][2], int buf, int nq) {
#pragma unroll
        for (int fn = 0; fn < 2; fn++)
#pragma unroll
            for (int kk = 0; kk < 2; kk++) {
                int row = nq * 128 + wc * 32 + fn * 16 + c;
                bf[fn][kk] = *(const bh8*)(Bs + buf * 16384 + row * 64 +
                                           ((((kk << 2) + g) ^ (row & 7)) << 3));
            }
    };
    f4v a00[4][2] = {}, a01[4][2] = {}, a10[4][2] = {}, a11[4][2] = {};
    auto MQ = [&](f4v (&acc)[4][2], bh8 (&bb)[2][2]) {
#pragma unroll
        for (int kk = 0; kk < 2; kk++)
#pragma unroll
            for (int fm = 0; fm < 4; fm++)
#pragma unroll
                for (int fn = 0; fn < 2; fn++)
                    acc[fm][fn] = __builtin_amdgcn_mfma_f32_16x16x32_bf16(
                        af[fm][kk], bb[fn][kk], acc[fm][fn], 0, 0, 0);
    };

#define GBAR asm volatile("s_barrier" ::: "memory")
#define VMC4 asm volatile("s_waitcnt vmcnt(4)" ::: "memory")
#define VMC0 asm volatile("s_waitcnt vmcnt(0)" ::: "memory")
#define LGK0 asm volatile("s_waitcnt lgkmcnt(0)" ::: "memory")
#define PHASE_TAIL(ACC, BF)                    \
    GBAR; LGK0;                                \
    __builtin_amdgcn_sched_barrier(0);         \
    __builtin_amdgcn_s_setprio(1);             \
    MQ(ACC, BF);                               \
    __builtin_amdgcn_s_setprio(0);             \
    GBAR;

    stage(Ab, As, 0, 0, 0); stage(Bb, Bs, 0, 0, 0);
    stage(Bb, Bs, 0, 1, 0); stage(Ab, As, 0, 1, 0);
    VMC0; GBAR;
    int nt = K >> 6;
    for (int t = 0; t < nt - 1; t++) {
        int buf = t & 1, nb = buf ^ 1;
        LDA(buf, 0); LDB(bf0, buf, 0);
        stage(Ab, As, nb, 0, t + 1);
        VMC4; PHASE_TAIL(a00, bf0);
        LDB(bf1, buf, 1);
        stage(Bb, Bs, nb, 0, t + 1);
        VMC4; PHASE_TAIL(a01, bf1);
        LDA(buf, 1);
        stage(Bb, Bs, nb, 1, t + 1);
        VMC4; PHASE_TAIL(a10, bf0);
        stage(Ab, As, nb, 1, t + 1);
        VMC4; PHASE_TAIL(a11, bf1);
    }
    {   // peeled last tile
        int buf = (nt - 1) & 1;
        VMC0; GBAR;
        LDA(buf, 0); LDB(bf0, buf, 0); LDB(bf1, buf, 1);
        MQ(a00, bf0); MQ(a01, bf1);
        LDA(buf, 1);
        MQ(a10, bf0); MQ(a11, bf1);
    }
    auto store = [&](f4v (&acc)[4][2], int mq, int nq) {
#pragma unroll
        for (int fm = 0; fm < 4; fm++)
#pragma unroll
            for (int j = 0; j < 4; j++) {
                int row = bm * 256 + mq * 128 + wr * 64 + fm * 16 + g * 4 + j;
                float sr = sa[row];
#pragma unroll
                for (int fn = 0; fn < 2; fn++) {
                    int col = bn * 256 + nq * 128 + wc * 32 + fn * 16 + c;
                    C[(size_t)row * N + col] = acc[fm][fn][j] * sr * sb[col];
                }
            }
    };
    store(a00, 0, 0); store(a01, 0, 1); store(a10, 1, 0); store(a11, 1, 1);
#undef GBAR
#undef VMC4
#undef VMC0
#undef LGK0
#undef PHASE_TAIL
}

// ---------------------------------------------------------------------------
// K path: int4 asym group quant (group=128 == one kv head) then RoPE, -> bf16.
// ---------------------------------------------------------------------------
__global__ __launch_bounds__(256) void k_quant_rope(
    const float* __restrict__ Kf, const int* __restrict__ pos,
    unsigned short* __restrict__ Kb, int rs)
{
    int wid = blockIdx.x * 4 + (threadIdx.x >> 6);
    int l = threadIdx.x & 63;
    int t = wid >> 3, kvh = wid & 7;
    const float* gp = Kf + (size_t)t * rs + kvh * 128;
    float x1 = gp[l], x2 = gp[l + 64];
    float mn = fminf(x1, x2), mx = fmaxf(x1, x2);
#pragma unroll
    for (int o = 32; o >= 1; o >>= 1) {
        mn = fminf(mn, __shfl_xor(mn, o));
        mx = fmaxf(mx, __shfl_xor(mx, o));
    }
    float sc = fmaxf((mx - mn) / 15.0f, 1e-8f);
    float q1 = fminf(fmaxf(rintf((x1 - mn) / sc), 0.f), 15.f);
    float q2 = fminf(fmaxf(rintf((x2 - mn) / sc), 0.f), 15.f);
    x1 = q1 * sc + mn;
    x2 = q2 * sc + mn;
    float f = exp2f(-(float)l * 0.3114307588956902f);   // log2(1e6)/64
    float ang = (float)pos[t] * f;
    float cs = cosf(ang), sn = sinf(ang);
    unsigned short* op = Kb + (size_t)t * KVD + kvh * 128;
    op[l]      = f2bf(x1 * cs - x2 * sn);
    op[l + 64] = f2bf(x2 * cs + x1 * sn);
}

// Q RoPE; folds softmax scale 1/sqrt(128)*log2(e) into Q (single rounding).
__global__ __launch_bounds__(256) void q_rope(
    const float* __restrict__ Qf, const int* __restrict__ pos,
    unsigned short* __restrict__ Qb, int rs)
{
    const float QSCL = (float)(0.08838834764831845 * 1.4426950408889634);
    int wid = blockIdx.x * 4 + (threadIdx.x >> 6);
    int l = threadIdx.x & 63;
    int t = wid >> 5, h = wid & 31;
    const float* gp = Qf + (size_t)t * rs + h * 128;
    float x1 = gp[l], x2 = gp[l + 64];
    float f = exp2f(-(float)l * 0.3114307588956902f);
    float ang = (float)pos[t] * f;
    float cs = cosf(ang), sn = sinf(ang);
    unsigned short* op = Qb + (size_t)t * HID + h * 128;
    op[l]      = f2bf((x1 * cs - x2 * sn) * QSCL);
    op[l + 64] = f2bf((x2 * cs + x1 * sn) * QSCL);
}

// V int4 group quant + transpose -> Vbt[kvh*128+d][t] fused (kills Vbq buffer)
__global__ __launch_bounds__(256) void v_quant_t(
    const float* __restrict__ Vf, int rs, unsigned short* __restrict__ Vbt)
{
    __shared__ unsigned short T[64][136];
    int t0 = blockIdx.x * 64;
    int kvh = blockIdx.y;
    int tid = threadIdx.x;
    int r = tid >> 2, q4 = tid & 3;          // 4 lanes per token row
    const float* gp = Vf + (size_t)(t0 + r) * rs + kvh * 128 + q4 * 32;
    float v[32];
#pragma unroll
    for (int i = 0; i < 8; i++) {
        float4 f = ((const float4*)gp)[i];
        v[4*i+0] = f.x; v[4*i+1] = f.y; v[4*i+2] = f.z; v[4*i+3] = f.w;
    }
    float mn = v[0], mx = v[0];
#pragma unroll
    for (int i = 1; i < 32; i++) { mn = fminf(mn, v[i]); mx = fmaxf(mx, v[i]); }
    mn = fminf(mn, __shfl_xor(mn, 1)); mx = fmaxf(mx, __shfl_xor(mx, 1));
    mn = fminf(mn, __shfl_xor(mn, 2)); mx = fmaxf(mx, __shfl_xor(mx, 2));
    float sc = fmaxf((mx - mn) / 15.0f, 1e-8f);
#pragma unroll
    for (int i = 0; i < 32; i++) {
        float q = fminf(fmaxf(rintf((v[i] - mn) / sc), 0.f), 15.f);
        T[r][q4 * 32 + i] = f2bf(q * sc + mn);
    }
    __syncthreads();
    int d = tid >> 1, hf = tid & 1;
#pragma unroll
    for (int b = 0; b < 4; b++) {
        us8 o;
#pragma unroll
        for (int j = 0; j < 8; j++) o[j] = T[hf * 32 + b * 8 + j][d];
        *(us8*)(Vbt + (size_t)(kvh * 128 + d) * SQ + t0 + hf * 32 + b * 8) = o;
    }
}

// ---------------------------------------------------------------------------
// Causal GQA flash attention, swapped-operand MFMA, QBLK=128.
// Block = (128-row Q tile, head); 4 waves x 32 q-rows (2 x 16-col B-frags).
// K tile DMA'd (global_load_lds, pre-swizzled source) into double-buffered LDS;
// V^T reg-staged into single-buffered LDS.  Each K/V fragment read feeds TWO
// MFMAs (2 q-groups) -> LDS bytes per FLOP halved vs QBLK=64.
// Grid (head, 16) with mirrored qb mapping pairs heavy+light blocks per CU.
// ---------------------------------------------------------------------------
__global__ __launch_bounds__(256, 2) void attn_kernel(
    const unsigned short* __restrict__ Qb, const unsigned short* __restrict__ Kb,
    const unsigned short* __restrict__ Vbt, float* __restrict__ AO)
{
    int h = blockIdx.x;
    int y = blockIdx.y;
    int qb = (y < 8) ? (15 - y) : (y - 8);         // heavy+light pairing per CU
    int kvh = h >> 2;                              // NREP=4, consecutive repeat
    int tid = threadIdx.x;
    int l = tid & 63, w = tid >> 6;
    int g = l >> 4, c = l & 15;
    __shared__ unsigned short Ks[2 * 8192];        // 2 x (64 keys x 128 d), swz
    __shared__ unsigned short Vt[128 * 64];        // V^T tile, chunk^(row&7) swz
    __shared__ unsigned short Plds[4][2][16][72];  // per-wave P rows, 2 q-groups
    int qbase = qb * 128 + w * 32;
    int nt = 2 * qb + 2;

    // K staging: DMA, linear LDS dest, swizzle applied on the global source
    auto stageK = [&](int buf, int kv0) {
#pragma unroll
        for (int i = 0; i < 4; i++) {
            int e = (i * 256 + tid) * 8;           // 0..8191
            int row = e >> 7, chunk = (e >> 3) & 15;
            gl2lds16(Kb + (size_t)(kv0 + row) * KVD + kvh * 128 + ((chunk ^ (row & 15)) << 3),
                     Ks + buf * 8192 + e);
        }
    };
    us8 vreg[4];
    auto stageV = [&](int kv0) {
#pragma unroll
        for (int i = 0; i < 4; i++) {
            int e = (i * 256 + tid) * 8;
            int r = e >> 6, cc = e & 63;
            vreg[i] = *(const us8*)(Vbt + (size_t)(kvh * 128 + r) * SQ + kv0 + cc);
        }
    };
    auto writeV = [&]() {
#pragma unroll
        for (int i = 0; i < 4; i++) {
            int e = (i * 256 + tid) * 8;
            int rv = e >> 6, chv = (e >> 3) & 7;
            *(us8*)(Vt + rv * 64 + ((chv ^ (rv & 7)) << 3)) = vreg[i];
        }
    };

    stageK(0, 0);
    stageV(0);

    bh8 qfA[4], qfB[4];
    {
        const unsigned short* qa = Qb + (size_t)(qbase + c) * HID + h * 128;
        const unsigned short* qp = Qb + (size_t)(qbase + 16 + c) * HID + h * 128;
#pragma unroll
        for (int kk = 0; kk < 4; kk++) {
            qfA[kk] = *(const bh8*)(qa + kk * 32 + g * 8);
            qfB[kk] = *(const bh8*)(qp + kk * 32 + g * 8);
        }
    }
    writeV();
    asm volatile("s_waitcnt vmcnt(0)" ::: "memory");
    __syncthreads();

    f4v accA[8] = {}, accB[8] = {};
    float mrunA = -1e30f, lrunA = 0.f, mrunB = -1e30f, lrunB = 0.f;

    for (int t = 0; t < nt; t++) {
        int kv0 = t * 64;
        int buf = t & 1;
        if (t < nt - 1) { stageK(buf ^ 1, kv0 + 64); stageV(kv0 + 64); }
        // S = K Q^T (swapped): sf[n][j] = S[key kv0+n*16+g*4+j][qcol]
        f4v sfA[4], sfB[4];
        __builtin_amdgcn_s_setprio(1);
#pragma unroll
        for (int n = 0; n < 4; n++) {
            f4v aA = {}, aB = {};
            int rowk = n * 16 + c;
#pragma unroll
            for (int kk = 0; kk < 4; kk++) {
                bh8 kf = *(const bh8*)(Ks + buf * 8192 + rowk * 128 +
                                       (((kk * 4 + g) ^ (rowk & 15)) << 3));
                aA = __builtin_amdgcn_mfma_f32_16x16x32_bf16(kf, qfA[kk], aA, 0, 0, 0);
                aB = __builtin_amdgcn_mfma_f32_16x16x32_bf16(kf, qfB[kk], aB, 0, 0, 0);
            }
            sfA[n] = aA; sfB[n] = aB;
        }
        __builtin_amdgcn_s_setprio(0);
        // causal mask (only near-diagonal tiles reach these conditions)
        if (kv0 + 63 > qbase) {
            int qrow = qbase + c;
#pragma unroll
            for (int n = 0; n < 4; n++)
#pragma unroll
                for (int j = 0; j < 4; j++)
                    if (kv0 + n * 16 + g * 4 + j > qrow) sfA[n][j] = -1e30f;
        }
        if (kv0 + 63 > qbase + 16) {
            int qrow = qbase + 16 + c;
#pragma unroll
            for (int n = 0; n < 4; n++)
#pragma unroll
                for (int j = 0; j < 4; j++)
                    if (kv0 + n * 16 + g * 4 + j > qrow) sfB[n][j] = -1e30f;
        }
        // softmax per q-group (in-lane reduce + cross-g shuffles)
        auto softmax = [&](f4v (&sf)[4], float& mrun, float& lrun, f4v (&acc)[8],
                           unsigned short* PW) {
            float pmax = sf[0][0];
#pragma unroll
            for (int n = 0; n < 4; n++)
#pragma unroll
                for (int j = 0; j < 4; j++) pmax = fmaxf(pmax, sf[n][j]);
            pmax = fmaxf(pmax, __shfl_xor(pmax, 16));
            pmax = fmaxf(pmax, __shfl_xor(pmax, 32));
            if (__any(pmax - mrun > 8.0f)) {       // defer-max (T13)
                float mnew = fmaxf(mrun, pmax);
                float alpha = exp2f(mrun - mnew);
                mrun = mnew;
                lrun *= alpha;
#pragma unroll
                for (int n = 0; n < 8; n++) acc[n] *= alpha;
            }
            float rsum = 0.f;
#pragma unroll
            for (int n = 0; n < 4; n++)
#pragma unroll
                for (int j = 0; j < 4; j++) {
                    float pv = exp2f(sf[n][j] - mrun);
                    sf[n][j] = pv;
                    rsum += pv;
                }
            rsum += __shfl_xor(rsum, 16);
            rsum += __shfl_xor(rsum, 32);
            lrun += rsum;
#pragma unroll
            for (int n = 0; n < 4; n++) {
                uint2 u;
                u.x = cvtpk_bf16(sf[n][0], sf[n][1]);
                u.y = cvtpk_bf16(sf[n][2], sf[n][3]);
                *(uint2*)(PW + c * 72 + n * 16 + g * 4) = u;
            }
        };
        softmax(sfA, mrunA, lrunA, accA, &Plds[w][0][0][0]);
        softmax(sfB, mrunB, lrunB, accB, &Plds[w][1][0][0]);
        // PV (swapped): acc += mfma(V^T rows, P rows); vf shared by both groups
        __builtin_amdgcn_s_setprio(1);
#pragma unroll
        for (int kk = 0; kk < 2; kk++) {
            bh8 pbA = *(const bh8*)(&Plds[w][0][c][kk * 32 + g * 8]);
            bh8 pbB = *(const bh8*)(&Plds[w][1][c][kk * 32 + g * 8]);
#pragma unroll
            for (int n = 0; n < 8; n++) {
                int rowv = n * 16 + c;
                bh8 vf = *(const bh8*)(Vt + rowv * 64 + (((kk * 4 + g) ^ (rowv & 7)) << 3));
                accA[n] = __builtin_amdgcn_mfma_f32_16x16x32_bf16(vf, pbA, accA[n], 0, 0, 0);
                accB[n] = __builtin_amdgcn_mfma_f32_16x16x32_bf16(vf, pbB, accB[n], 0, 0, 0);
            }
        }
        __builtin_amdgcn_s_setprio(0);
        if (t < nt - 1) {
            __syncthreads();      // all waves done reading Ks[buf] and Vt
            writeV();             // waits vreg loads (compiler vmcnt)
            asm volatile("s_waitcnt vmcnt(0)" ::: "memory");   // K DMA complete
            __syncthreads();      // tile t+1 LDS visible
        }
    }
    // epilogue: lane holds O[d][q]; contiguous d -> float4 stores
    float invA = 1.0f / lrunA, invB = 1.0f / lrunB;
#pragma unroll
    for (int n = 0; n < 8; n++) {
        f4v oA = accA[n] * invA;
        f4v oB = accB[n] * invB;
        *(f4v*)(AO + (size_t)(qbase + c) * HID + h * 128 + n * 16 + g * 4) = oA;
        *(f4v*)(AO + (size_t)(qbase + 16 + c) * HID + h * 128 + n * 16 + g * 4) = oB;
    }
}

// ---------------------------------------------------------------------------
extern "C" void kernel_launch(void* const* d_in, const int* in_sizes, int n_in,
                              void* d_out, int out_size, void* d_ws, size_t ws_size,
                              hipStream_t stream)
{
    const float* x   = (const float*)d_in[0];
    const int*   pos = (const int*)d_in[1];
    const float* rw  = (const float*)d_in[2];
    const float* Wq  = (const float*)d_in[3];
    const float* Wk  = (const float*)d_in[4];
    const float* Wv  = (const float*)d_in[5];
    const float* Wo  = (const float*)d_in[6];
    float* out = (float*)d_out;

    char* p = (char*)d_ws;
    auto alloc = [&](size_t bytes) -> void* {
        void* r = (void*)p;
        p += (bytes + 255) & ~(size_t)255;
        return r;
    };
    unsigned short* xq    = (unsigned short*)alloc((size_t)SQ * HID * 2);
    float*          sx    = (float*)alloc(SQ * 4);
    unsigned short* wqkv  = (unsigned short*)alloc((size_t)QKVN * HID * 2);
    unsigned short* woq   = (unsigned short*)alloc((size_t)HID * HID * 2);
    float*          swqkv = (float*)alloc(QKVN * 4);
    float*          swo   = (float*)alloc(HID * 4);
    float*          QKVf  = (float*)alloc((size_t)SQ * QKVN * 4);  // reused: AO, attq
    unsigned short* Qb    = (unsigned short*)alloc((size_t)SQ * HID * 2);
    unsigned short* Kb    = (unsigned short*)alloc((size_t)SQ * KVD * 2);
    unsigned short* Vbt   = (unsigned short*)alloc((size_t)SQ * KVD * 2);
    float*          sa    = (float*)alloc(SQ * 4);

    size_t need = (size_t)(p - (char*)d_ws);
    if (ws_size < need) {
        // sentinel: absmax ~3.4e38 tells us ws was too small
        hipMemsetAsync(d_out, 0x7f, 4, stream);
        return;
    }
    float*          AO   = QKVf;                                   // QKV consumed before attn
    unsigned short* attq = (unsigned short*)(QKVf + (size_t)SQ * HID);
    // 1) all 4 weight fake-quants in one dispatch
    wquant4<<<QKVN + HID, 256, 0, stream>>>(Wq, Wk, Wv, Wo, wqkv, woq, swqkv, swo);
    // 2) rmsnorm + per-token int8 fake-quant
    rowquant_kernel<<<SQ, 256, 0, stream>>>(x, rw, xq, sx, 1);
    // 3) merged QKV projection (exact integer math in bf16 MFMA)
    gemm256<<<dim3((SQ / 256) * (QKVN / 256)), 512, 0, stream>>>(
        xq, wqkv, sx, swqkv, QKVf, SQ, QKVN, HID, SQ / 256);
    // 4) K int4 quant + RoPE ; Q RoPE (pre-scaled) ; V int4 quant + transpose
    k_quant_rope<<<SQ * NKVH / 4, 256, 0, stream>>>(QKVf + HID, pos, Kb, QKVN);
    q_rope<<<SQ * NHEAD / 4, 256, 0, stream>>>(QKVf, pos, Qb, QKVN);
    v_quant_t<<<dim3(SQ / 64, NKVH), 256, 0, stream>>>(QKVf + HID + KVD, QKVN, Vbt);
    // 5) causal GQA flash attention (swapped-operand, QBLK=128)
    attn_kernel<<<dim3(NHEAD, 16), 256, 0, stream>>>(Qb, Kb, Vbt, AO);
    // 6) per-token int8 fake-quant of attention output + O projection
    rowquant_kernel<<<SQ, 256, 0, stream>>>(AO, nullptr, attq, sa, 0);
    gemm256<<<dim3((SQ / 256) * (HID / 256)), 512, 0, stream>>>(
        attq, woq, sa, swo, out, SQ, HID, HID, SQ / 256);
}

// Round 6
// 357.565 us; speedup vs baseline: 2.6758x; 1.1577x over previous
//
#include <hip/hip_runtime.h>

// ---------------------------------------------------------------------------
// QMixtralAttention: rmsnorm -> int8 fake-quant -> QKV proj (exact int-in-bf16
// MFMA, merged N=6144, BM=128 full-fill 256-block schedule) -> int4 KV quant ->
// RoPE -> causal GQA flash attention (swapped-operand MFMA) -> int8 -> O proj.
// ---------------------------------------------------------------------------

#define SQ   2048
#define HID  4096
#define NHEAD 32
#define HDIM 128
#define NKVH 8
#define KVD  1024   // NKVH*HDIM
#define QKVN 6144   // HID + 2*KVD

typedef __attribute__((ext_vector_type(8))) short          bh8;   // 8 x bf16 bits (MFMA operand)
typedef __attribute__((ext_vector_type(8))) unsigned short us8;
typedef __attribute__((ext_vector_type(4))) unsigned short us4;
typedef __attribute__((ext_vector_type(4))) float          f4v;

__device__ __forceinline__ unsigned short f2bf(float f) {
    unsigned u = __float_as_uint(f);
    u += 0x7fffu + ((u >> 16) & 1u);          // RNE
    return (unsigned short)(u >> 16);
}

__device__ __forceinline__ unsigned cvtpk_bf16(float a, float b) {
    unsigned r;
    asm("v_cvt_pk_bf16_f32 %0, %1, %2" : "=v"(r) : "v"(a), "v"(b));
    return r;   // lo = bf16(a), hi = bf16(b)  (RNE)
}

// async global -> LDS, 16B per lane (m97 pattern)
__device__ __forceinline__ void gl2lds16(const unsigned short* g, unsigned short* l) {
    __builtin_amdgcn_global_load_lds(
        (const __attribute__((address_space(1))) unsigned int*)g,
        (__attribute__((address_space(3))) unsigned int*)l, 16, 0, 0);
}

template<int N> __device__ __forceinline__ void vmc() {
    if constexpr (N == 0) asm volatile("s_waitcnt vmcnt(0)" ::: "memory");
    else if constexpr (N == 2) asm volatile("s_waitcnt vmcnt(2)" ::: "memory");
    else if constexpr (N == 4) asm volatile("s_waitcnt vmcnt(4)" ::: "memory");
    else if constexpr (N == 6) asm volatile("s_waitcnt vmcnt(6)" ::: "memory");
    else if constexpr (N == 8) asm volatile("s_waitcnt vmcnt(8)" ::: "memory");
}

// ---------------------------------------------------------------------------
// Shared per-row (4096-wide) symmetric int8 fake-quant body.
// ---------------------------------------------------------------------------
__device__ __forceinline__ void rq_body(const float* __restrict__ xr, float v[16],
                                        unsigned short* __restrict__ dst,
                                        float* __restrict__ sout,
                                        float* red, int tid, int l, int wv)
{
    float am = 0.f;
#pragma unroll
    for (int i = 0; i < 16; i++) am = fmaxf(am, fabsf(v[i]));
#pragma unroll
    for (int o = 32; o >= 1; o >>= 1) am = fmaxf(am, __shfl_xor(am, o));
    if (l == 0) red[wv] = am;
    __syncthreads();
    am = fmaxf(fmaxf(red[0], red[1]), fmaxf(red[2], red[3]));
    float s = fmaxf(am / 127.0f, 1e-8f);
    if (tid == 0) *sout = s;
    unsigned short qb[16];
#pragma unroll
    for (int i = 0; i < 16; i++) {
        float q = rintf(v[i] / s);                 // true division: match jnp rounding
        q = fminf(fmaxf(q, -127.f), 127.f);
        qb[i] = f2bf(q);                           // integer <=127: exact in bf16
    }
#pragma unroll
    for (int i = 0; i < 4; i++) {
        us4 o4 = { qb[4*i+0], qb[4*i+1], qb[4*i+2], qb[4*i+3] };
        ((us4*)dst)[i * 256 + tid] = o4;
    }
}

// Per-row int8 fake-quant with optional fused RMSNorm (hidden states / attn out)
__global__ __launch_bounds__(256) void rowquant_kernel(
    const float* __restrict__ X, const float* __restrict__ Wg,
    unsigned short* __restrict__ Q, float* __restrict__ Sout, int do_rms)
{
    int row = blockIdx.x;
    int tid = threadIdx.x;
    int l = tid & 63, wv = tid >> 6;
    const float* xr = X + (size_t)row * 4096;
    float v[16];
#pragma unroll
    for (int i = 0; i < 4; i++) {
        float4 f = ((const float4*)xr)[i * 256 + tid];
        v[4*i+0] = f.x; v[4*i+1] = f.y; v[4*i+2] = f.z; v[4*i+3] = f.w;
    }
    __shared__ float red[4];
    if (do_rms) {
        float ss = 0.f;
#pragma unroll
        for (int i = 0; i < 16; i++) ss += v[i] * v[i];
#pragma unroll
        for (int o = 32; o >= 1; o >>= 1) ss += __shfl_xor(ss, o);
        if (l == 0) red[wv] = ss;
        __syncthreads();
        float tot = red[0] + red[1] + red[2] + red[3];
        float rs = rsqrtf(tot * (1.0f / 4096.0f) + 1e-5f);
        __syncthreads();   // red is reused below
#pragma unroll
        for (int i = 0; i < 4; i++) {
            float4 wf = ((const float4*)Wg)[i * 256 + tid];
            v[4*i+0] = v[4*i+0] * rs * wf.x;
            v[4*i+1] = v[4*i+1] * rs * wf.y;
            v[4*i+2] = v[4*i+2] * rs * wf.z;
            v[4*i+3] = v[4*i+3] * rs * wf.w;
        }
    }
    rq_body(xr, v, Q + (size_t)row * 4096, Sout + row, red, tid, l, wv);
}

// All 4 weight matrices fake-quantized in ONE dispatch (10240 rows).
__global__ __launch_bounds__(256) void wquant4(
    const float* __restrict__ Wq, const float* __restrict__ Wk,
    const float* __restrict__ Wv, const float* __restrict__ Wo,
    unsigned short* __restrict__ wqkv, unsigned short* __restrict__ woq,
    float* __restrict__ swqkv, float* __restrict__ swo)
{
    int row = blockIdx.x;
    const float* src; unsigned short* dst; float* sout;
    if (row < HID)          { src = Wq + (size_t)row * HID;             dst = wqkv + (size_t)row * HID; sout = swqkv + row; }
    else if (row < HID+KVD) { src = Wk + (size_t)(row - HID) * HID;     dst = wqkv + (size_t)row * HID; sout = swqkv + row; }
    else if (row < QKVN)    { src = Wv + (size_t)(row - HID - KVD) * HID; dst = wqkv + (size_t)row * HID; sout = swqkv + row; }
    else { int r = row - QKVN; src = Wo + (size_t)r * HID;              dst = woq + (size_t)r * HID;  sout = swo + r; }
    int tid = threadIdx.x;
    int l = tid & 63, wv = tid >> 6;
    float v[16];
#pragma unroll
    for (int i = 0; i < 4; i++) {
        float4 f = ((const float4*)src)[i * 256 + tid];
        v[4*i+0] = f.x; v[4*i+1] = f.y; v[4*i+2] = f.z; v[4*i+3] = f.w;
    }
    __shared__ float red[4];
    rq_body(src, v, dst, sout, red, tid, l, wv);
}

// ---------------------------------------------------------------------------
// bf16 GEMM, BM=128 x BN (384 or 256), BK=64, 8 waves (2M x 4N, wave=64 x BN/4).
// Grid sized to EXACTLY 256 blocks (full CU fill, 1 block/CU).
// NQ = BN/128 phases per K-tile; phase = { vmcnt(counted); s_barrier;
// stage unit(s) of tile t+1 (global_load_lds, pre-swizzled source);
// ds_read frags; lgkmcnt(0); setprio(1); 16 MFMA; setprio(0) }.
// Ledger: unit staged in phase p of iter t is waited in phase p of iter t+1
// (NQ-phase slack).  vmcnt: P1 = 2*(NQ-1), else 2*NQ; last tile drains to 0.
// C[m][n] = sa[m]*sb[n] * sum_k A[m][k]*B[n][k]   (both K-major)
// ---------------------------------------------------------------------------
template<int BN>
__global__ __launch_bounds__(512, 1) void gemm128(
    const unsigned short* __restrict__ A, const unsigned short* __restrict__ B,
    const float* __restrict__ sa, const float* __restrict__ sb,
    float* __restrict__ C, int M, int N, int K, int NBM)
{
    constexpr int NQ = BN / 128;
    __shared__ unsigned short As[2 * 8192];        // 2 buf x 128 rows x 64
    __shared__ unsigned short Bs[2 * BN * 64];     // 2 buf x BN rows x 64
    int tid = threadIdx.x;
    int l = tid & 63, wid = tid >> 6;
    int wr = wid >> 2, wc = wid & 3;               // 2M x 4N waves
    int g = l >> 4, c = l & 15;
    int wg = blockIdx.x;
    int cpx = (int)gridDim.x >> 3;                 // grid == 256, multiple of 8
    int swz = (wg & 7) * cpx + (wg >> 3);
    int bm = swz % NBM, bn = swz / NBM;
    const unsigned short* Ab = A + (size_t)bm * 128 * K;
    const unsigned short* Bb = B + (size_t)bn * BN * K;

    auto stageA = [&](int buf, int tt) {
#pragma unroll
        for (int r = 0; r < 2; r++) {
            int e = (r * 512 + tid) * 8;
            int row = e >> 6, chunk = (e >> 3) & 7;
            gl2lds16(Ab + (size_t)row * K + tt * 64 + ((chunk ^ (row & 7)) << 3),
                     As + buf * 8192 + e);
        }
    };
    auto stageB = [&](int buf, int u, int tt) {
#pragma unroll
        for (int r = 0; r < 2; r++) {
            int e = (r * 512 + tid) * 8;
            int row = e >> 6, chunk = (e >> 3) & 7;
            gl2lds16(Bb + (size_t)(u * 128 + row) * K + tt * 64 + ((chunk ^ (row & 7)) << 3),
                     Bs + buf * (BN * 64) + u * 8192 + e);
        }
    };
    // prologue: tile 0 staged oldest-first in read order A, B0, B1(, B2)
    stageA(0, 0);
#pragma unroll
    for (int u = 0; u < NQ; u++) stageB(0, u, 0);

    f4v acc[4][2 * NQ] = {};
    bh8 af[4][2];
    int nt = K >> 6;
    for (int t = 0; t < nt; t++) {
        int buf = t & 1;
        bool last = (t == nt - 1);
#pragma unroll
        for (int nq = 0; nq < NQ; nq++) {
            if (last) { if (nq == 0) vmc<0>(); }
            else if (nq == 0) vmc<2 * (NQ - 1)>();
            else vmc<2 * NQ>();
            asm volatile("s_barrier" ::: "memory");
            if (!last) {
                if (nq == 0) { stageA(buf ^ 1, t + 1); stageB(buf ^ 1, 0, t + 1); }
                else stageB(buf ^ 1, nq, t + 1);
            }
            if (nq == 0) {
#pragma unroll
                for (int fm = 0; fm < 4; fm++)
#pragma unroll
                    for (int kk = 0; kk < 2; kk++) {
                        int row = wr * 64 + fm * 16 + c;
                        af[fm][kk] = *(const bh8*)(As + buf * 8192 + row * 64 +
                                                   ((((kk << 2) + g) ^ (row & 7)) << 3));
                    }
            }
            bh8 bf[2][2];
#pragma unroll
            for (int fn = 0; fn < 2; fn++)
#pragma unroll
                for (int kk = 0; kk < 2; kk++) {
                    int row = nq * 128 + wc * 32 + fn * 16 + c;
                    bf[fn][kk] = *(const bh8*)(Bs + buf * (BN * 64) + row * 64 +
                                               ((((kk << 2) + g) ^ (row & 7)) << 3));
                }
            asm volatile("s_waitcnt lgkmcnt(0)" ::: "memory");
            __builtin_amdgcn_sched_barrier(0);
            __builtin_amdgcn_s_setprio(1);
#pragma unroll
            for (int kk = 0; kk < 2; kk++)
#pragma unroll
                for (int fm = 0; fm < 4; fm++)
#pragma unroll
                    for (int fn = 0; fn < 2; fn++)
                        acc[fm][nq * 2 + fn] = __builtin_amdgcn_mfma_f32_16x16x32_bf16(
                            af[fm][kk], bf[fn][kk], acc[fm][nq * 2 + fn], 0, 0, 0);
            __builtin_amdgcn_s_setprio(0);
        }
    }
    // epilogue: C[row][col] = acc * sa[row] * sb[col]
#pragma unroll
    for (int fm = 0; fm < 4; fm++)
#pragma unroll
        for (int j = 0; j < 4; j++) {
            int row = bm * 128 + wr * 64 + fm * 16 + g * 4 + j;
            float sr = sa[row];
#pragma unroll
            for (int q = 0; q < 2 * NQ; q++) {
                int col = bn * BN + (q >> 1) * 128 + wc * 32 + (q & 1) * 16 + c;
                C[(size_t)row * N + col] = acc[fm][q][j] * sr * sb[col];
            }
        }
}

// ---------------------------------------------------------------------------
// K path: int4 asym group quant (group=128 == one kv head) then RoPE, -> bf16.
// ---------------------------------------------------------------------------
__global__ __launch_bounds__(256) void k_quant_rope(
    const float* __restrict__ Kf, const int* __restrict__ pos,
    unsigned short* __restrict__ Kb, int rs)
{
    int wid = blockIdx.x * 4 + (threadIdx.x >> 6);
    int l = threadIdx.x & 63;
    int t = wid >> 3, kvh = wid & 7;
    const float* gp = Kf + (size_t)t * rs + kvh * 128;
    float x1 = gp[l], x2 = gp[l + 64];
    float mn = fminf(x1, x2), mx = fmaxf(x1, x2);
#pragma unroll
    for (int o = 32; o >= 1; o >>= 1) {
        mn = fminf(mn, __shfl_xor(mn, o));
        mx = fmaxf(mx, __shfl_xor(mx, o));
    }
    float sc = fmaxf((mx - mn) / 15.0f, 1e-8f);
    float q1 = fminf(fmaxf(rintf((x1 - mn) / sc), 0.f), 15.f);
    float q2 = fminf(fmaxf(rintf((x2 - mn) / sc), 0.f), 15.f);
    x1 = q1 * sc + mn;
    x2 = q2 * sc + mn;
    float f = exp2f(-(float)l * 0.3114307588956902f);   // log2(1e6)/64
    float ang = (float)pos[t] * f;
    float cs = cosf(ang), sn = sinf(ang);
    unsigned short* op = Kb + (size_t)t * KVD + kvh * 128;
    op[l]      = f2bf(x1 * cs - x2 * sn);
    op[l + 64] = f2bf(x2 * cs + x1 * sn);
}

// Q RoPE; folds softmax scale 1/sqrt(128)*log2(e) into Q (single rounding).
__global__ __launch_bounds__(256) void q_rope(
    const float* __restrict__ Qf, const int* __restrict__ pos,
    unsigned short* __restrict__ Qb, int rs)
{
    const float QSCL = (float)(0.08838834764831845 * 1.4426950408889634);
    int wid = blockIdx.x * 4 + (threadIdx.x >> 6);
    int l = threadIdx.x & 63;
    int t = wid >> 5, h = wid & 31;
    const float* gp = Qf + (size_t)t * rs + h * 128;
    float x1 = gp[l], x2 = gp[l + 64];
    float f = exp2f(-(float)l * 0.3114307588956902f);
    float ang = (float)pos[t] * f;
    float cs = cosf(ang), sn = sinf(ang);
    unsigned short* op = Qb + (size_t)t * HID + h * 128;
    op[l]      = f2bf((x1 * cs - x2 * sn) * QSCL);
    op[l + 64] = f2bf((x2 * cs + x1 * sn) * QSCL);
}

// V int4 group quant + transpose -> Vbt[kvh*128+d][t] fused
__global__ __launch_bounds__(256) void v_quant_t(
    const float* __restrict__ Vf, int rs, unsigned short* __restrict__ Vbt)
{
    __shared__ unsigned short T[64][136];
    int t0 = blockIdx.x * 64;
    int kvh = blockIdx.y;
    int tid = threadIdx.x;
    int r = tid >> 2, q4 = tid & 3;          // 4 lanes per token row
    const float* gp = Vf + (size_t)(t0 + r) * rs + kvh * 128 + q4 * 32;
    float v[32];
#pragma unroll
    for (int i = 0; i < 8; i++) {
        float4 f = ((const float4*)gp)[i];
        v[4*i+0] = f.x; v[4*i+1] = f.y; v[4*i+2] = f.z; v[4*i+3] = f.w;
    }
    float mn = v[0], mx = v[0];
#pragma unroll
    for (int i = 1; i < 32; i++) { mn = fminf(mn, v[i]); mx = fmaxf(mx, v[i]); }
    mn = fminf(mn, __shfl_xor(mn, 1)); mx = fmaxf(mx, __shfl_xor(mx, 1));
    mn = fminf(mn, __shfl_xor(mn, 2)); mx = fmaxf(mx, __shfl_xor(mx, 2));
    float sc = fmaxf((mx - mn) / 15.0f, 1e-8f);
#pragma unroll
    for (int i = 0; i < 32; i++) {
        float q = fminf(fmaxf(rintf((v[i] - mn) / sc), 0.f), 15.f);
        T[r][q4 * 32 + i] = f2bf(q * sc + mn);
    }
    __syncthreads();
    int d = tid >> 1, hf = tid & 1;
#pragma unroll
    for (int b = 0; b < 4; b++) {
        us8 o;
#pragma unroll
        for (int j = 0; j < 8; j++) o[j] = T[hf * 32 + b * 8 + j][d];
        *(us8*)(Vbt + (size_t)(kvh * 128 + d) * SQ + t0 + hf * 32 + b * 8) = o;
    }
}

// ---------------------------------------------------------------------------
// Causal GQA flash attention, swapped-operand MFMA, QBLK=128.
// (unchanged from round 5)
// ---------------------------------------------------------------------------
__global__ __launch_bounds__(256, 2) void attn_kernel(
    const unsigned short* __restrict__ Qb, const unsigned short* __restrict__ Kb,
    const unsigned short* __restrict__ Vbt, float* __restrict__ AO)
{
    int h = blockIdx.x;
    int y = blockIdx.y;
    int qb = (y < 8) ? (15 - y) : (y - 8);         // heavy+light pairing per CU
    int kvh = h >> 2;                              // NREP=4, consecutive repeat
    int tid = threadIdx.x;
    int l = tid & 63, w = tid >> 6;
    int g = l >> 4, c = l & 15;
    __shared__ unsigned short Ks[2 * 8192];        // 2 x (64 keys x 128 d), swz
    __shared__ unsigned short Vt[128 * 64];        // V^T tile, chunk^(row&7) swz
    __shared__ unsigned short Plds[4][2][16][72];  // per-wave P rows, 2 q-groups
    int qbase = qb * 128 + w * 32;
    int nt = 2 * qb + 2;

    auto stageK = [&](int buf, int kv0) {
#pragma unroll
        for (int i = 0; i < 4; i++) {
            int e = (i * 256 + tid) * 8;           // 0..8191
            int row = e >> 7, chunk = (e >> 3) & 15;
            gl2lds16(Kb + (size_t)(kv0 + row) * KVD + kvh * 128 + ((chunk ^ (row & 15)) << 3),
                     Ks + buf * 8192 + e);
        }
    };
    us8 vreg[4];
    auto stageV = [&](int kv0) {
#pragma unroll
        for (int i = 0; i < 4; i++) {
            int e = (i * 256 + tid) * 8;
            int r = e >> 6, cc = e & 63;
            vreg[i] = *(const us8*)(Vbt + (size_t)(kvh * 128 + r) * SQ + kv0 + cc);
        }
    };
    auto writeV = [&]() {
#pragma unroll
        for (int i = 0; i < 4; i++) {
            int e = (i * 256 + tid) * 8;
            int rv = e >> 6, chv = (e >> 3) & 7;
            *(us8*)(Vt + rv * 64 + ((chv ^ (rv & 7)) << 3)) = vreg[i];
        }
    };

    stageK(0, 0);
    stageV(0);

    bh8 qfA[4], qfB[4];
    {
        const unsigned short* qa = Qb + (size_t)(qbase + c) * HID + h * 128;
        const unsigned short* qp = Qb + (size_t)(qbase + 16 + c) * HID + h * 128;
#pragma unroll
        for (int kk = 0; kk < 4; kk++) {
            qfA[kk] = *(const bh8*)(qa + kk * 32 + g * 8);
            qfB[kk] = *(const bh8*)(qp + kk * 32 + g * 8);
        }
    }
    writeV();
    asm volatile("s_waitcnt vmcnt(0)" ::: "memory");
    __syncthreads();

    f4v accA[8] = {}, accB[8] = {};
    float mrunA = -1e30f, lrunA = 0.f, mrunB = -1e30f, lrunB = 0.f;

    for (int t = 0; t < nt; t++) {
        int kv0 = t * 64;
        int buf = t & 1;
        if (t < nt - 1) { stageK(buf ^ 1, kv0 + 64); stageV(kv0 + 64); }
        f4v sfA[4], sfB[4];
        __builtin_amdgcn_s_setprio(1);
#pragma unroll
        for (int n = 0; n < 4; n++) {
            f4v aA = {}, aB = {};
            int rowk = n * 16 + c;
#pragma unroll
            for (int kk = 0; kk < 4; kk++) {
                bh8 kf = *(const bh8*)(Ks + buf * 8192 + rowk * 128 +
                                       (((kk * 4 + g) ^ (rowk & 15)) << 3));
                aA = __builtin_amdgcn_mfma_f32_16x16x32_bf16(kf, qfA[kk], aA, 0, 0, 0);
                aB = __builtin_amdgcn_mfma_f32_16x16x32_bf16(kf, qfB[kk], aB, 0, 0, 0);
            }
            sfA[n] = aA; sfB[n] = aB;
        }
        __builtin_amdgcn_s_setprio(0);
        if (kv0 + 63 > qbase) {
            int qrow = qbase + c;
#pragma unroll
            for (int n = 0; n < 4; n++)
#pragma unroll
                for (int j = 0; j < 4; j++)
                    if (kv0 + n * 16 + g * 4 + j > qrow) sfA[n][j] = -1e30f;
        }
        if (kv0 + 63 > qbase + 16) {
            int qrow = qbase + 16 + c;
#pragma unroll
            for (int n = 0; n < 4; n++)
#pragma unroll
                for (int j = 0; j < 4; j++)
                    if (kv0 + n * 16 + g * 4 + j > qrow) sfB[n][j] = -1e30f;
        }
        auto softmax = [&](f4v (&sf)[4], float& mrun, float& lrun, f4v (&acc)[8],
                           unsigned short* PW) {
            float pmax = sf[0][0];
#pragma unroll
            for (int n = 0; n < 4; n++)
#pragma unroll
                for (int j = 0; j < 4; j++) pmax = fmaxf(pmax, sf[n][j]);
            pmax = fmaxf(pmax, __shfl_xor(pmax, 16));
            pmax = fmaxf(pmax, __shfl_xor(pmax, 32));
            if (__any(pmax - mrun > 8.0f)) {       // defer-max (T13)
                float mnew = fmaxf(mrun, pmax);
                float alpha = exp2f(mrun - mnew);
                mrun = mnew;
                lrun *= alpha;
#pragma unroll
                for (int n = 0; n < 8; n++) acc[n] *= alpha;
            }
            float rsum = 0.f;
#pragma unroll
            for (int n = 0; n < 4; n++)
#pragma unroll
                for (int j = 0; j < 4; j++) {
                    float pv = exp2f(sf[n][j] - mrun);
                    sf[n][j] = pv;
                    rsum += pv;
                }
            rsum += __shfl_xor(rsum, 16);
            rsum += __shfl_xor(rsum, 32);
            lrun += rsum;
#pragma unroll
            for (int n = 0; n < 4; n++) {
                uint2 u;
                u.x = cvtpk_bf16(sf[n][0], sf[n][1]);
                u.y = cvtpk_bf16(sf[n][2], sf[n][3]);
                *(uint2*)(PW + c * 72 + n * 16 + g * 4) = u;
            }
        };
        softmax(sfA, mrunA, lrunA, accA, &Plds[w][0][0][0]);
        softmax(sfB, mrunB, lrunB, accB, &Plds[w][1][0][0]);
        __builtin_amdgcn_s_setprio(1);
#pragma unroll
        for (int kk = 0; kk < 2; kk++) {
            bh8 pbA = *(const bh8*)(&Plds[w][0][c][kk * 32 + g * 8]);
            bh8 pbB = *(const bh8*)(&Plds[w][1][c][kk * 32 + g * 8]);
#pragma unroll
            for (int n = 0; n < 8; n++) {
                int rowv = n * 16 + c;
                bh8 vf = *(const bh8*)(Vt + rowv * 64 + (((kk * 4 + g) ^ (rowv & 7)) << 3));
                accA[n] = __builtin_amdgcn_mfma_f32_16x16x32_bf16(vf, pbA, accA[n], 0, 0, 0);
                accB[n] = __builtin_amdgcn_mfma_f32_16x16x32_bf16(vf, pbB, accB[n], 0, 0, 0);
            }
        }
        __builtin_amdgcn_s_setprio(0);
        if (t < nt - 1) {
            __syncthreads();
            writeV();
            asm volatile("s_waitcnt vmcnt(0)" ::: "memory");
            __syncthreads();
        }
    }
    float invA = 1.0f / lrunA, invB = 1.0f / lrunB;
#pragma unroll
    for (int n = 0; n < 8; n++) {
        f4v oA = accA[n] * invA;
        f4v oB = accB[n] * invB;
        *(f4v*)(AO + (size_t)(qbase + c) * HID + h * 128 + n * 16 + g * 4) = oA;
        *(f4v*)(AO + (size_t)(qbase + 16 + c) * HID + h * 128 + n * 16 + g * 4) = oB;
    }
}

// ---------------------------------------------------------------------------
extern "C" void kernel_launch(void* const* d_in, const int* in_sizes, int n_in,
                              void* d_out, int out_size, void* d_ws, size_t ws_size,
                              hipStream_t stream)
{
    const float* x   = (const float*)d_in[0];
    const int*   pos = (const int*)d_in[1];
    const float* rw  = (const float*)d_in[2];
    const float* Wq  = (const float*)d_in[3];
    const float* Wk  = (const float*)d_in[4];
    const float* Wv  = (const float*)d_in[5];
    const float* Wo  = (const float*)d_in[6];
    float* out = (float*)d_out;

    char* p = (char*)d_ws;
    auto alloc = [&](size_t bytes) -> void* {
        void* r = (void*)p;
        p += (bytes + 255) & ~(size_t)255;
        return r;
    };
    unsigned short* xq    = (unsigned short*)alloc((size_t)SQ * HID * 2);
    float*          sx    = (float*)alloc(SQ * 4);
    unsigned short* wqkv  = (unsigned short*)alloc((size_t)QKVN * HID * 2);
    unsigned short* woq   = (unsigned short*)alloc((size_t)HID * HID * 2);
    float*          swqkv = (float*)alloc(QKVN * 4);
    float*          swo   = (float*)alloc(HID * 4);
    float*          QKVf  = (float*)alloc((size_t)SQ * QKVN * 4);  // reused: AO, attq
    unsigned short* Qb    = (unsigned short*)alloc((size_t)SQ * HID * 2);
    unsigned short* Kb    = (unsigned short*)alloc((size_t)SQ * KVD * 2);
    unsigned short* Vbt   = (unsigned short*)alloc((size_t)SQ * KVD * 2);
    float*          sa    = (float*)alloc(SQ * 4);

    size_t need = (size_t)(p - (char*)d_ws);
    if (ws_size < need) {
        // sentinel: absmax ~3.4e38 tells us ws was too small
        hipMemsetAsync(d_out, 0x7f, 4, stream);
        return;
    }
    float*          AO   = QKVf;                                   // QKV consumed before attn
    unsigned short* attq = (unsigned short*)(QKVf + (size_t)SQ * HID);
    // 1) all 4 weight fake-quants in one dispatch
    wquant4<<<QKVN + HID, 256, 0, stream>>>(Wq, Wk, Wv, Wo, wqkv, woq, swqkv, swo);
    // 2) rmsnorm + per-token int8 fake-quant
    rowquant_kernel<<<SQ, 256, 0, stream>>>(x, rw, xq, sx, 1);
    // 3) merged QKV projection: BM=128, BN=384 -> 16x16 = 256 blocks (full fill)
    gemm128<384><<<dim3((SQ / 128) * (QKVN / 384)), 512, 0, stream>>>(
        xq, wqkv, sx, swqkv, QKVf, SQ, QKVN, HID, SQ / 128);
    // 4) K int4 quant + RoPE ; Q RoPE (pre-scaled) ; V int4 quant + transpose
    k_quant_rope<<<SQ * NKVH / 4, 256, 0, stream>>>(QKVf + HID, pos, Kb, QKVN);
    q_rope<<<SQ * NHEAD / 4, 256, 0, stream>>>(QKVf, pos, Qb, QKVN);
    v_quant_t<<<dim3(SQ / 64, NKVH), 256, 0, stream>>>(QKVf + HID + KVD, QKVN, Vbt);
    // 5) causal GQA flash attention (swapped-operand, QBLK=128)
    attn_kernel<<<dim3(NHEAD, 16), 256, 0, stream>>>(Qb, Kb, Vbt, AO);
    // 6) per-token int8 fake-quant of attention output + O projection
    rowquant_kernel<<<SQ, 256, 0, stream>>>(AO, nullptr, attq, sa, 0);
    // O projection: BM=128, BN=256 -> 16x16 = 256 blocks (full fill)
    gemm128<256><<<dim3((SQ / 128) * (HID / 256)), 512, 0, stream>>>(
        attq, woq, sa, swo, out, SQ, HID, HID, SQ / 128);
}

// Round 7
// 270.449 us; speedup vs baseline: 3.5377x; 1.3221x over previous
//
#include <hip/hip_runtime.h>

// ---------------------------------------------------------------------------
// QMixtralAttention: rmsnorm -> int8 quant -> QKV proj (EXACT i8 MFMA i32-acc,
// merged N=6144, BK=128 counted-vmcnt schedule) -> int4 KV quant -> RoPE ->
// causal GQA flash attention (swapped-operand bf16 MFMA) -> int8 -> O proj.
// ---------------------------------------------------------------------------

#define SQ   2048
#define HID  4096
#define NHEAD 32
#define HDIM 128
#define NKVH 8
#define KVD  1024   // NKVH*HDIM
#define QKVN 6144   // HID + 2*KVD

typedef __attribute__((ext_vector_type(8))) short          bh8;   // 8 x bf16 bits
typedef __attribute__((ext_vector_type(8))) unsigned short us8;
typedef __attribute__((ext_vector_type(4))) float          f4v;
typedef __attribute__((ext_vector_type(4))) int            i32x4; // i8 MFMA A/B/C

__device__ __forceinline__ unsigned short f2bf(float f) {
    unsigned u = __float_as_uint(f);
    u += 0x7fffu + ((u >> 16) & 1u);          // RNE
    return (unsigned short)(u >> 16);
}

__device__ __forceinline__ unsigned cvtpk_bf16(float a, float b) {
    unsigned r;
    asm("v_cvt_pk_bf16_f32 %0, %1, %2" : "=v"(r) : "v"(a), "v"(b));
    return r;
}

// async global -> LDS, 16B per lane (m97 pattern)
__device__ __forceinline__ void gl2lds16(const void* g, void* l) {
    __builtin_amdgcn_global_load_lds(
        (const __attribute__((address_space(1))) unsigned int*)g,
        (__attribute__((address_space(3))) unsigned int*)l, 16, 0, 0);
}

template<int N> __device__ __forceinline__ void vmc() {
    if constexpr (N == 0) asm volatile("s_waitcnt vmcnt(0)" ::: "memory");
    else if constexpr (N == 2) asm volatile("s_waitcnt vmcnt(2)" ::: "memory");
    else if constexpr (N == 4) asm volatile("s_waitcnt vmcnt(4)" ::: "memory");
    else if constexpr (N == 6) asm volatile("s_waitcnt vmcnt(6)" ::: "memory");
    else if constexpr (N == 8) asm volatile("s_waitcnt vmcnt(8)" ::: "memory");
}

// ---------------------------------------------------------------------------
// Shared per-row (4096-wide) symmetric int8 quant body -> packed int8 + scale.
// ---------------------------------------------------------------------------
__device__ __forceinline__ void rq_body(float v[16],
                                        char* __restrict__ dst,
                                        float* __restrict__ sout,
                                        float* red, int tid, int l, int wv)
{
    float am = 0.f;
#pragma unroll
    for (int i = 0; i < 16; i++) am = fmaxf(am, fabsf(v[i]));
#pragma unroll
    for (int o = 32; o >= 1; o >>= 1) am = fmaxf(am, __shfl_xor(am, o));
    if (l == 0) red[wv] = am;
    __syncthreads();
    am = fmaxf(fmaxf(red[0], red[1]), fmaxf(red[2], red[3]));
    float s = fmaxf(am / 127.0f, 1e-8f);
    if (tid == 0) *sout = s;
#pragma unroll
    for (int i = 0; i < 4; i++) {
        unsigned pk = 0;
#pragma unroll
        for (int j = 0; j < 4; j++) {
            float q = rintf(v[4*i+j] / s);         // true division: match jnp rounding
            q = fminf(fmaxf(q, -127.f), 127.f);
            pk |= ((unsigned)((int)q & 0xff)) << (8 * j);
        }
        ((unsigned*)dst)[i * 256 + tid] = pk;      // bytes i*1024 + tid*4
    }
}

// Per-row int8 quant with optional fused RMSNorm (hidden states / attn out)
__global__ __launch_bounds__(256) void rowquant_kernel(
    const float* __restrict__ X, const float* __restrict__ Wg,
    char* __restrict__ Q, float* __restrict__ Sout, int do_rms)
{
    int row = blockIdx.x;
    int tid = threadIdx.x;
    int l = tid & 63, wv = tid >> 6;
    const float* xr = X + (size_t)row * 4096;
    float v[16];
#pragma unroll
    for (int i = 0; i < 4; i++) {
        float4 f = ((const float4*)xr)[i * 256 + tid];
        v[4*i+0] = f.x; v[4*i+1] = f.y; v[4*i+2] = f.z; v[4*i+3] = f.w;
    }
    __shared__ float red[4];
    if (do_rms) {
        float ss = 0.f;
#pragma unroll
        for (int i = 0; i < 16; i++) ss += v[i] * v[i];
#pragma unroll
        for (int o = 32; o >= 1; o >>= 1) ss += __shfl_xor(ss, o);
        if (l == 0) red[wv] = ss;
        __syncthreads();
        float tot = red[0] + red[1] + red[2] + red[3];
        float rs = rsqrtf(tot * (1.0f / 4096.0f) + 1e-5f);
        __syncthreads();   // red is reused below
#pragma unroll
        for (int i = 0; i < 4; i++) {
            float4 wf = ((const float4*)Wg)[i * 256 + tid];
            v[4*i+0] = v[4*i+0] * rs * wf.x;
            v[4*i+1] = v[4*i+1] * rs * wf.y;
            v[4*i+2] = v[4*i+2] * rs * wf.z;
            v[4*i+3] = v[4*i+3] * rs * wf.w;
        }
    }
    rq_body(v, Q + (size_t)row * 4096, Sout + row, red, tid, l, wv);
}

// All 4 weight matrices quantized in ONE dispatch (10240 rows) -> int8.
__global__ __launch_bounds__(256) void wquant4(
    const float* __restrict__ Wq, const float* __restrict__ Wk,
    const float* __restrict__ Wv, const float* __restrict__ Wo,
    char* __restrict__ wqkv, char* __restrict__ woq,
    float* __restrict__ swqkv, float* __restrict__ swo)
{
    int row = blockIdx.x;
    const float* src; char* dst; float* sout;
    if (row < HID)          { src = Wq + (size_t)row * HID;             dst = wqkv + (size_t)row * HID; sout = swqkv + row; }
    else if (row < HID+KVD) { src = Wk + (size_t)(row - HID) * HID;     dst = wqkv + (size_t)row * HID; sout = swqkv + row; }
    else if (row < QKVN)    { src = Wv + (size_t)(row - HID - KVD) * HID; dst = wqkv + (size_t)row * HID; sout = swqkv + row; }
    else { int r = row - QKVN; src = Wo + (size_t)r * HID;              dst = woq + (size_t)r * HID;  sout = swo + r; }
    int tid = threadIdx.x;
    int l = tid & 63, wv = tid >> 6;
    float v[16];
#pragma unroll
    for (int i = 0; i < 4; i++) {
        float4 f = ((const float4*)src)[i * 256 + tid];
        v[4*i+0] = f.x; v[4*i+1] = f.y; v[4*i+2] = f.z; v[4*i+3] = f.w;
    }
    __shared__ float red[4];
    rq_body(v, dst, sout, red, tid, l, wv);
}

// ---------------------------------------------------------------------------
// int8 GEMM (EXACT i32 accum): C[m][n] = sa[m]*sb[n] * sum_k A[m][k]*B[n][k].
// mfma_i32_16x16x64_i8, BM=128 x BN (384/256), BK=128, 8 waves (2M x 4N).
// Grid = exactly 256 blocks (full CU fill).  NQ = BN/128 phases per K-tile:
// { vmcnt(counted); s_barrier; stage tile t+1 unit(s) via global_load_lds
//   (pre-swizzled source, chunk^(row&7) on 128B rows); ds_read frags;
//   lgkmcnt(0); setprio(1); 16 MFMA; setprio(0) }.
// Ledger (2 loads/unit; phase0 issues A+B0=4, else 2): wait = 2(NQ-1) at
// phase0, 2NQ else; peeled last tile drains vmcnt(0) once.
// ---------------------------------------------------------------------------
template<int BN>
__global__ __launch_bounds__(512, 1) void gemm128i8(
    const char* __restrict__ A, const char* __restrict__ B,
    const float* __restrict__ sa, const float* __restrict__ sb,
    float* __restrict__ C, int M, int N, int K, int NBM)
{
    constexpr int NQ  = BN / 128;
    constexpr int BSZ = BN * 128;              // bytes per B buffer
    __shared__ char As[2 * 16384];             // 2 buf x 128 rows x 128 B
    __shared__ char Bs[2 * BSZ];
    int tid = threadIdx.x;
    int l = tid & 63, wid = tid >> 6;
    int wr = wid >> 2, wc = wid & 3;           // 2M x 4N waves
    int g = l >> 4, c = l & 15;
    int wg = blockIdx.x;
    int cpx = (int)gridDim.x >> 3;             // grid == 256, multiple of 8
    int swz = (wg & 7) * cpx + (wg >> 3);
    int bm = swz % NBM, bn = swz / NBM;
    const char* Ab = A + (size_t)bm * 128 * K;
    const char* Bb = B + (size_t)bn * BN * K;

    auto stageA = [&](int buf, int tt) {
#pragma unroll
        for (int r = 0; r < 2; r++) {
            int e = (r * 512 + tid) * 16;      // 0..16383
            int row = e >> 7, chunk = (e >> 4) & 7;
            gl2lds16(Ab + (size_t)row * K + tt * 128 + ((chunk ^ (row & 7)) << 4),
                     As + buf * 16384 + e);
        }
    };
    auto stageB = [&](int buf, int u, int tt) {
#pragma unroll
        for (int r = 0; r < 2; r++) {
            int e = (r * 512 + tid) * 16;
            int row = e >> 7, chunk = (e >> 4) & 7;
            gl2lds16(Bb + (size_t)(u * 128 + row) * K + tt * 128 + ((chunk ^ (row & 7)) << 4),
                     Bs + buf * BSZ + u * 16384 + e);
        }
    };
    i32x4 af[4][2];
    auto LDA = [&](int buf) {
#pragma unroll
        for (int fm = 0; fm < 4; fm++)
#pragma unroll
            for (int kk = 0; kk < 2; kk++) {
                int row = wr * 64 + fm * 16 + c;
                af[fm][kk] = *(const i32x4*)(As + buf * 16384 + row * 128 +
                                             (((kk * 4 + g) ^ (row & 7)) << 4));
            }
    };

    // prologue: tile 0 staged in read order A, B0 .. B(NQ-1)
    stageA(0, 0);
#pragma unroll
    for (int u = 0; u < NQ; u++) stageB(0, u, 0);

    i32x4 acc[4][2 * NQ] = {};
    int nt = K >> 7;
    for (int t = 0; t < nt; t++) {
        int buf = t & 1;
        bool last = (t == nt - 1);
#pragma unroll
        for (int nq = 0; nq < NQ; nq++) {
            if (last) { if (nq == 0) vmc<0>(); }
            else if (nq == 0) vmc<2 * (NQ - 1)>();
            else vmc<2 * NQ>();
            asm volatile("s_barrier" ::: "memory");
            if (!last) {
                if (nq == 0) { stageA(buf ^ 1, t + 1); stageB(buf ^ 1, 0, t + 1); }
                else stageB(buf ^ 1, nq, t + 1);
            }
            if (nq == 0) LDA(buf);
            i32x4 bf[2][2];
#pragma unroll
            for (int fn = 0; fn < 2; fn++)
#pragma unroll
                for (int kk = 0; kk < 2; kk++) {
                    int rowu = wc * 32 + fn * 16 + c;   // within unit nq
                    bf[fn][kk] = *(const i32x4*)(Bs + buf * BSZ + nq * 16384 +
                                                 rowu * 128 +
                                                 (((kk * 4 + g) ^ (rowu & 7)) << 4));
                }
            asm volatile("s_waitcnt lgkmcnt(0)" ::: "memory");
            __builtin_amdgcn_sched_barrier(0);
            __builtin_amdgcn_s_setprio(1);
#pragma unroll
            for (int kk = 0; kk < 2; kk++)
#pragma unroll
                for (int fm = 0; fm < 4; fm++)
#pragma unroll
                    for (int fn = 0; fn < 2; fn++)
                        acc[fm][nq * 2 + fn] = __builtin_amdgcn_mfma_i32_16x16x64_i8(
                            af[fm][kk], bf[fn][kk], acc[fm][nq * 2 + fn], 0, 0, 0);
            __builtin_amdgcn_s_setprio(0);
        }
    }
    // epilogue: C[row][col] = (float)acc * sa[row] * sb[col]
#pragma unroll
    for (int fm = 0; fm < 4; fm++)
#pragma unroll
        for (int j = 0; j < 4; j++) {
            int row = bm * 128 + wr * 64 + fm * 16 + g * 4 + j;
            float sr = sa[row];
#pragma unroll
            for (int q = 0; q < 2 * NQ; q++) {
                int col = bn * BN + (q >> 1) * 128 + wc * 32 + (q & 1) * 16 + c;
                C[(size_t)row * N + col] = (float)acc[fm][q][j] * sr * sb[col];
            }
        }
}

// ---------------------------------------------------------------------------
// K path: int4 asym group quant (group=128 == one kv head) then RoPE, -> bf16.
// ---------------------------------------------------------------------------
__global__ __launch_bounds__(256) void k_quant_rope(
    const float* __restrict__ Kf, const int* __restrict__ pos,
    unsigned short* __restrict__ Kb, int rs)
{
    int wid = blockIdx.x * 4 + (threadIdx.x >> 6);
    int l = threadIdx.x & 63;
    int t = wid >> 3, kvh = wid & 7;
    const float* gp = Kf + (size_t)t * rs + kvh * 128;
    float x1 = gp[l], x2 = gp[l + 64];
    float mn = fminf(x1, x2), mx = fmaxf(x1, x2);
#pragma unroll
    for (int o = 32; o >= 1; o >>= 1) {
        mn = fminf(mn, __shfl_xor(mn, o));
        mx = fmaxf(mx, __shfl_xor(mx, o));
    }
    float sc = fmaxf((mx - mn) / 15.0f, 1e-8f);
    float q1 = fminf(fmaxf(rintf((x1 - mn) / sc), 0.f), 15.f);
    float q2 = fminf(fmaxf(rintf((x2 - mn) / sc), 0.f), 15.f);
    x1 = q1 * sc + mn;
    x2 = q2 * sc + mn;
    float f = exp2f(-(float)l * 0.3114307588956902f);   // log2(1e6)/64
    float ang = (float)pos[t] * f;
    float cs = cosf(ang), sn = sinf(ang);
    unsigned short* op = Kb + (size_t)t * KVD + kvh * 128;
    op[l]      = f2bf(x1 * cs - x2 * sn);
    op[l + 64] = f2bf(x2 * cs + x1 * sn);
}

// Q RoPE; folds softmax scale 1/sqrt(128)*log2(e) into Q (single rounding).
__global__ __launch_bounds__(256) void q_rope(
    const float* __restrict__ Qf, const int* __restrict__ pos,
    unsigned short* __restrict__ Qb, int rs)
{
    const float QSCL = (float)(0.08838834764831845 * 1.4426950408889634);
    int wid = blockIdx.x * 4 + (threadIdx.x >> 6);
    int l = threadIdx.x & 63;
    int t = wid >> 5, h = wid & 31;
    const float* gp = Qf + (size_t)t * rs + h * 128;
    float x1 = gp[l], x2 = gp[l + 64];
    float f = exp2f(-(float)l * 0.3114307588956902f);
    float ang = (float)pos[t] * f;
    float cs = cosf(ang), sn = sinf(ang);
    unsigned short* op = Qb + (size_t)t * HID + h * 128;
    op[l]      = f2bf((x1 * cs - x2 * sn) * QSCL);
    op[l + 64] = f2bf((x2 * cs + x1 * sn) * QSCL);
}

// V int4 group quant + transpose -> Vbt[kvh*128+d][t] fused
__global__ __launch_bounds__(256) void v_quant_t(
    const float* __restrict__ Vf, int rs, unsigned short* __restrict__ Vbt)
{
    __shared__ unsigned short T[64][136];
    int t0 = blockIdx.x * 64;
    int kvh = blockIdx.y;
    int tid = threadIdx.x;
    int r = tid >> 2, q4 = tid & 3;          // 4 lanes per token row
    const float* gp = Vf + (size_t)(t0 + r) * rs + kvh * 128 + q4 * 32;
    float v[32];
#pragma unroll
    for (int i = 0; i < 8; i++) {
        float4 f = ((const float4*)gp)[i];
        v[4*i+0] = f.x; v[4*i+1] = f.y; v[4*i+2] = f.z; v[4*i+3] = f.w;
    }
    float mn = v[0], mx = v[0];
#pragma unroll
    for (int i = 1; i < 32; i++) { mn = fminf(mn, v[i]); mx = fmaxf(mx, v[i]); }
    mn = fminf(mn, __shfl_xor(mn, 1)); mx = fmaxf(mx, __shfl_xor(mx, 1));
    mn = fminf(mn, __shfl_xor(mn, 2)); mx = fmaxf(mx, __shfl_xor(mx, 2));
    float sc = fmaxf((mx - mn) / 15.0f, 1e-8f);
#pragma unroll
    for (int i = 0; i < 32; i++) {
        float q = fminf(fmaxf(rintf((v[i] - mn) / sc), 0.f), 15.f);
        T[r][q4 * 32 + i] = f2bf(q * sc + mn);
    }
    __syncthreads();
    int d = tid >> 1, hf = tid & 1;
#pragma unroll
    for (int b = 0; b < 4; b++) {
        us8 o;
#pragma unroll
        for (int j = 0; j < 8; j++) o[j] = T[hf * 32 + b * 8 + j][d];
        *(us8*)(Vbt + (size_t)(kvh * 128 + d) * SQ + t0 + hf * 32 + b * 8) = o;
    }
}

// ---------------------------------------------------------------------------
// Causal GQA flash attention, swapped-operand MFMA, QBLK=128 (unchanged).
// ---------------------------------------------------------------------------
__global__ __launch_bounds__(256, 2) void attn_kernel(
    const unsigned short* __restrict__ Qb, const unsigned short* __restrict__ Kb,
    const unsigned short* __restrict__ Vbt, float* __restrict__ AO)
{
    int h = blockIdx.x;
    int y = blockIdx.y;
    int qb = (y < 8) ? (15 - y) : (y - 8);         // heavy+light pairing per CU
    int kvh = h >> 2;                              // NREP=4, consecutive repeat
    int tid = threadIdx.x;
    int l = tid & 63, w = tid >> 6;
    int g = l >> 4, c = l & 15;
    __shared__ unsigned short Ks[2 * 8192];        // 2 x (64 keys x 128 d), swz
    __shared__ unsigned short Vt[128 * 64];        // V^T tile, chunk^(row&7) swz
    __shared__ unsigned short Plds[4][2][16][72];  // per-wave P rows, 2 q-groups
    int qbase = qb * 128 + w * 32;
    int nt = 2 * qb + 2;

    auto stageK = [&](int buf, int kv0) {
#pragma unroll
        for (int i = 0; i < 4; i++) {
            int e = (i * 256 + tid) * 8;           // 0..8191
            int row = e >> 7, chunk = (e >> 3) & 15;
            gl2lds16(Kb + (size_t)(kv0 + row) * KVD + kvh * 128 + ((chunk ^ (row & 15)) << 3),
                     Ks + buf * 8192 + e);
        }
    };
    us8 vreg[4];
    auto stageV = [&](int kv0) {
#pragma unroll
        for (int i = 0; i < 4; i++) {
            int e = (i * 256 + tid) * 8;
            int r = e >> 6, cc = e & 63;
            vreg[i] = *(const us8*)(Vbt + (size_t)(kvh * 128 + r) * SQ + kv0 + cc);
        }
    };
    auto writeV = [&]() {
#pragma unroll
        for (int i = 0; i < 4; i++) {
            int e = (i * 256 + tid) * 8;
            int rv = e >> 6, chv = (e >> 3) & 7;
            *(us8*)(Vt + rv * 64 + ((chv ^ (rv & 7)) << 3)) = vreg[i];
        }
    };

    stageK(0, 0);
    stageV(0);

    bh8 qfA[4], qfB[4];
    {
        const unsigned short* qa = Qb + (size_t)(qbase + c) * HID + h * 128;
        const unsigned short* qp = Qb + (size_t)(qbase + 16 + c) * HID + h * 128;
#pragma unroll
        for (int kk = 0; kk < 4; kk++) {
            qfA[kk] = *(const bh8*)(qa + kk * 32 + g * 8);
            qfB[kk] = *(const bh8*)(qp + kk * 32 + g * 8);
        }
    }
    writeV();
    asm volatile("s_waitcnt vmcnt(0)" ::: "memory");
    __syncthreads();

    f4v accA[8] = {}, accB[8] = {};
    float mrunA = -1e30f, lrunA = 0.f, mrunB = -1e30f, lrunB = 0.f;

    for (int t = 0; t < nt; t++) {
        int kv0 = t * 64;
        int buf = t & 1;
        if (t < nt - 1) { stageK(buf ^ 1, kv0 + 64); stageV(kv0 + 64); }
        f4v sfA[4], sfB[4];
        __builtin_amdgcn_s_setprio(1);
#pragma unroll
        for (int n = 0; n < 4; n++) {
            f4v aA = {}, aB = {};
            int rowk = n * 16 + c;
#pragma unroll
            for (int kk = 0; kk < 4; kk++) {
                bh8 kf = *(const bh8*)(Ks + buf * 8192 + rowk * 128 +
                                       (((kk * 4 + g) ^ (rowk & 15)) << 3));
                aA = __builtin_amdgcn_mfma_f32_16x16x32_bf16(kf, qfA[kk], aA, 0, 0, 0);
                aB = __builtin_amdgcn_mfma_f32_16x16x32_bf16(kf, qfB[kk], aB, 0, 0, 0);
            }
            sfA[n] = aA; sfB[n] = aB;
        }
        __builtin_amdgcn_s_setprio(0);
        if (kv0 + 63 > qbase) {
            int qrow = qbase + c;
#pragma unroll
            for (int n = 0; n < 4; n++)
#pragma unroll
                for (int j = 0; j < 4; j++)
                    if (kv0 + n * 16 + g * 4 + j > qrow) sfA[n][j] = -1e30f;
        }
        if (kv0 + 63 > qbase + 16) {
            int qrow = qbase + 16 + c;
#pragma unroll
            for (int n = 0; n < 4; n++)
#pragma unroll
                for (int j = 0; j < 4; j++)
                    if (kv0 + n * 16 + g * 4 + j > qrow) sfB[n][j] = -1e30f;
        }
        auto softmax = [&](f4v (&sf)[4], float& mrun, float& lrun, f4v (&acc)[8],
                           unsigned short* PW) {
            float pmax = sf[0][0];
#pragma unroll
            for (int n = 0; n < 4; n++)
#pragma unroll
                for (int j = 0; j < 4; j++) pmax = fmaxf(pmax, sf[n][j]);
            pmax = fmaxf(pmax, __shfl_xor(pmax, 16));
            pmax = fmaxf(pmax, __shfl_xor(pmax, 32));
            if (__any(pmax - mrun > 8.0f)) {       // defer-max (T13)
                float mnew = fmaxf(mrun, pmax);
                float alpha = exp2f(mrun - mnew);
                mrun = mnew;
                lrun *= alpha;
#pragma unroll
                for (int n = 0; n < 8; n++) acc[n] *= alpha;
            }
            float rsum = 0.f;
#pragma unroll
            for (int n = 0; n < 4; n++)
#pragma unroll
                for (int j = 0; j < 4; j++) {
                    float pv = exp2f(sf[n][j] - mrun);
                    sf[n][j] = pv;
                    rsum += pv;
                }
            rsum += __shfl_xor(rsum, 16);
            rsum += __shfl_xor(rsum, 32);
            lrun += rsum;
#pragma unroll
            for (int n = 0; n < 4; n++) {
                uint2 u;
                u.x = cvtpk_bf16(sf[n][0], sf[n][1]);
                u.y = cvtpk_bf16(sf[n][2], sf[n][3]);
                *(uint2*)(PW + c * 72 + n * 16 + g * 4) = u;
            }
        };
        softmax(sfA, mrunA, lrunA, accA, &Plds[w][0][0][0]);
        softmax(sfB, mrunB, lrunB, accB, &Plds[w][1][0][0]);
        __builtin_amdgcn_s_setprio(1);
#pragma unroll
        for (int kk = 0; kk < 2; kk++) {
            bh8 pbA = *(const bh8*)(&Plds[w][0][c][kk * 32 + g * 8]);
            bh8 pbB = *(const bh8*)(&Plds[w][1][c][kk * 32 + g * 8]);
#pragma unroll
            for (int n = 0; n < 8; n++) {
                int rowv = n * 16 + c;
                bh8 vf = *(const bh8*)(Vt + rowv * 64 + (((kk * 4 + g) ^ (rowv & 7)) << 3));
                accA[n] = __builtin_amdgcn_mfma_f32_16x16x32_bf16(vf, pbA, accA[n], 0, 0, 0);
                accB[n] = __builtin_amdgcn_mfma_f32_16x16x32_bf16(vf, pbB, accB[n], 0, 0, 0);
            }
        }
        __builtin_amdgcn_s_setprio(0);
        if (t < nt - 1) {
            __syncthreads();
            writeV();
            asm volatile("s_waitcnt vmcnt(0)" ::: "memory");
            __syncthreads();
        }
    }
    float invA = 1.0f / lrunA, invB = 1.0f / lrunB;
#pragma unroll
    for (int n = 0; n < 8; n++) {
        f4v oA = accA[n] * invA;
        f4v oB = accB[n] * invB;
        *(f4v*)(AO + (size_t)(qbase + c) * HID + h * 128 + n * 16 + g * 4) = oA;
        *(f4v*)(AO + (size_t)(qbase + 16 + c) * HID + h * 128 + n * 16 + g * 4) = oB;
    }
}

// ---------------------------------------------------------------------------
extern "C" void kernel_launch(void* const* d_in, const int* in_sizes, int n_in,
                              void* d_out, int out_size, void* d_ws, size_t ws_size,
                              hipStream_t stream)
{
    const float* x   = (const float*)d_in[0];
    const int*   pos = (const int*)d_in[1];
    const float* rw  = (const float*)d_in[2];
    const float* Wq  = (const float*)d_in[3];
    const float* Wk  = (const float*)d_in[4];
    const float* Wv  = (const float*)d_in[5];
    const float* Wo  = (const float*)d_in[6];
    float* out = (float*)d_out;

    char* p = (char*)d_ws;
    auto alloc = [&](size_t bytes) -> void* {
        void* r = (void*)p;
        p += (bytes + 255) & ~(size_t)255;
        return r;
    };
    char*           xq    = (char*)alloc((size_t)SQ * HID);
    float*          sx    = (float*)alloc(SQ * 4);
    char*           wqkv  = (char*)alloc((size_t)QKVN * HID);
    char*           woq   = (char*)alloc((size_t)HID * HID);
    float*          swqkv = (float*)alloc(QKVN * 4);
    float*          swo   = (float*)alloc(HID * 4);
    float*          QKVf  = (float*)alloc((size_t)SQ * QKVN * 4);  // reused: AO, attq
    unsigned short* Qb    = (unsigned short*)alloc((size_t)SQ * HID * 2);
    unsigned short* Kb    = (unsigned short*)alloc((size_t)SQ * KVD * 2);
    unsigned short* Vbt   = (unsigned short*)alloc((size_t)SQ * KVD * 2);
    float*          sa    = (float*)alloc(SQ * 4);

    size_t need = (size_t)(p - (char*)d_ws);
    if (ws_size < need) {
        // sentinel: absmax ~3.4e38 tells us ws was too small
        hipMemsetAsync(d_out, 0x7f, 4, stream);
        return;
    }
    float*          AO   = QKVf;                                   // QKV consumed before attn
    char*           attq = (char*)(QKVf + (size_t)SQ * HID);
    // 1) all 4 weight int8 quants in one dispatch
    wquant4<<<QKVN + HID, 256, 0, stream>>>(Wq, Wk, Wv, Wo, wqkv, woq, swqkv, swo);
    // 2) rmsnorm + per-token int8 quant
    rowquant_kernel<<<SQ, 256, 0, stream>>>(x, rw, xq, sx, 1);
    // 3) merged QKV projection: EXACT i8 MFMA; BM=128 BN=384 -> 256 blocks
    gemm128i8<384><<<dim3((SQ / 128) * (QKVN / 384)), 512, 0, stream>>>(
        xq, wqkv, sx, swqkv, QKVf, SQ, QKVN, HID, SQ / 128);
    // 4) K int4 quant + RoPE ; Q RoPE (pre-scaled) ; V int4 quant + transpose
    k_quant_rope<<<SQ * NKVH / 4, 256, 0, stream>>>(QKVf + HID, pos, Kb, QKVN);
    q_rope<<<SQ * NHEAD / 4, 256, 0, stream>>>(QKVf, pos, Qb, QKVN);
    v_quant_t<<<dim3(SQ / 64, NKVH), 256, 0, stream>>>(QKVf + HID + KVD, QKVN, Vbt);
    // 5) causal GQA flash attention (swapped-operand, QBLK=128)
    attn_kernel<<<dim3(NHEAD, 16), 256, 0, stream>>>(Qb, Kb, Vbt, AO);
    // 6) per-token int8 quant of attention output + O projection
    rowquant_kernel<<<SQ, 256, 0, stream>>>(AO, nullptr, attq, sa, 0);
    // O projection: BM=128 BN=256 -> 256 blocks
    gemm128i8<256><<<dim3((SQ / 128) * (HID / 256)), 512, 0, stream>>>(
        attq, woq, sa, swo, out, SQ, HID, HID, SQ / 128);
}